// Round 13
// baseline (337.795 us; speedup 1.0000x reference)
//
#include <hip/hip_runtime.h>

typedef unsigned short u16;
typedef unsigned int   u32;
typedef _Float16       f16;

typedef f16   f16x8 __attribute__((ext_vector_type(8)));
typedef f16   f16x4 __attribute__((ext_vector_type(4)));
typedef float f32x4 __attribute__((ext_vector_type(4)));

__device__ __forceinline__ f32x4 mfma16(f16x8 a, f16x8 b, f32x4 c){
  return __builtin_amdgcn_mfma_f32_16x16x32_f16(a, b, c, 0, 0, 0);
}

// async global->LDS, 16B per lane; LDS dest = wave-uniform base + lane*16 (linear)
__device__ __forceinline__ void glds16(const f16* g, f16* l){
  __builtin_amdgcn_global_load_lds(
      (const __attribute__((address_space(1))) void*)g,
      (__attribute__((address_space(3))) void*)l, 16, 0, 0);
}

__device__ __forceinline__ void barrier_f(){
  __builtin_amdgcn_s_barrier();
  asm volatile("" ::: "memory");
}

// ============ 2. ALL weight preps: mean/rstd computed from raw S/SS sums ============
__global__ __launch_bounds__(256) void k_prep_w_all(
    const float* __restrict__ qW,  const float* __restrict__ qB,
    const float* __restrict__ kW,  const float* __restrict__ kB,
    const float* __restrict__ q2W, const float* __restrict__ q2B,
    const float* __restrict__ k2W, const float* __restrict__ k2B,
    const float* __restrict__ vW,  const float* __restrict__ vB,
    const float* __restrict__ v2W, const float* __restrict__ v2B,
    const float* __restrict__ f1W, const float* __restrict__ f2W,
    const float* __restrict__ stats,
    f16* __restrict__ qw, f16* __restrict__ kw,
    f16* __restrict__ q2wh, f16* __restrict__ q2wl,
    f16* __restrict__ k2wh, f16* __restrict__ k2wl,
    f16* __restrict__ vw, f16* __restrict__ v2w,
    f16* __restrict__ f1w, f16* __restrict__ f2w,
    float* __restrict__ biasp)
{
  const int t = threadIdx.x;
  int rid = blockIdx.x * 32 + (t >> 3);
  const float *W; const float *B = nullptr;
  int side = -1, b = 0, o;
  f16 *oh; f16 *ol = nullptr; float* bs = nullptr;
  if(rid < 2048){
    b = rid >> 9; o = rid & 511;
    W = qW; B = qB; side = 0;
    oh = qw + (size_t)(b * 512 + o) * 512;
    bs = biasp + 0 * 2048 + b * 512 + o;
  } else if(rid < 4096){
    rid -= 2048; b = rid >> 9; o = rid & 511;
    W = kW; B = kB; side = 1;
    oh = kw + (size_t)(b * 512 + o) * 512;
    bs = biasp + 1 * 2048 + b * 512 + o;
  } else if(rid < 6144){
    rid -= 4096; b = rid >> 9; o = rid & 511;
    W = q2W; B = q2B; side = 0;
    oh = q2wh + (size_t)(b * 512 + o) * 512;
    ol = q2wl + (size_t)(b * 512 + o) * 512;
    bs = biasp + 4 * 2048 + b * 512 + o;
  } else if(rid < 8192){
    rid -= 6144; b = rid >> 9; o = rid & 511;
    W = k2W; B = k2B; side = 1;
    oh = k2wh + (size_t)(b * 512 + o) * 512;
    ol = k2wl + (size_t)(b * 512 + o) * 512;
    bs = biasp + 5 * 2048 + b * 512 + o;
  } else if(rid < 8704){
    o = rid - 8192; W = vW; B = vB;
    oh = vw + (size_t)o * 512;
    bs = biasp + 2 * 2048 + o;
  } else if(rid < 9216){
    o = rid - 8704; W = v2W; B = v2B;
    oh = v2w + (size_t)o * 512;
    bs = biasp + 3 * 2048 + o;
  } else if(rid < 9728){
    o = rid - 9216; W = f1W;
    oh = f1w + (size_t)o * 512;
  } else {
    o = rid - 9728; W = f2W;
    oh = f2w + (size_t)o * 512;
  }
  const float* Sv  = (side >= 0) ? stats + side * 4096 + b * 512 : nullptr;
  const float* SSv = Sv ? Sv + 2048 : nullptr;
  const int c0 = (t & 7) * 64;
  float dot = 0.f;
  #pragma unroll
  for(int i = 0; i < 64; i += 8){
    int c = c0 + i;
    float w[8];
    *(float4*)(w)     = *(const float4*)(W + (size_t)o * 512 + c);
    *(float4*)(w + 4) = *(const float4*)(W + (size_t)o * 512 + c + 4);
    f16x8 h8, l8;
    #pragma unroll
    for(int j = 0; j < 8; j++){
      float wp = w[j];
      if(side >= 0){
        float S = Sv[c + j], SS = SSv[c + j];
        float mean = S * (1.f / 4096.f);
        float r = rsqrtf((SS - S * mean) * (1.f / 4095.f) + 1e-5f);
        dot += wp * mean * r;
        wp *= r;
      }
      f16 h = (f16)wp;
      h8[j] = h; l8[j] = (f16)(wp - (float)h);
    }
    *(f16x8*)(oh + c) = h8;
    if(ol) *(f16x8*)(ol + c) = l8;
  }
  if(bs){
    dot += __shfl_xor(dot, 1); dot += __shfl_xor(dot, 2); dot += __shfl_xor(dot, 4);
    if((t & 7) == 0) *bs = B[o] - dot;
  }
}

// ============ 3. X prep: transpose + f16 hi/lo split + fused MVN stats (S/SS atomics) ============
__global__ __launch_bounds__(256) void k_prep_x(
    const float* __restrict__ content, const float* __restrict__ style,
    f16* __restrict__ cth, f16* __restrict__ ctl,
    f16* __restrict__ sth, f16* __restrict__ stl,
    float* __restrict__ stats)
{
  const int side = blockIdx.z;
  const int b = blockIdx.y;
  const int s0 = blockIdx.x * 128;
  const float* Xb = (side ? style : content) + (size_t)b * 512 * 4096;
  f16* Oh = (side ? sth : cth) + (size_t)b * 4096 * 512;
  f16* Ol = (side ? stl : ctl) + (size_t)b * 4096 * 512;
  float* Sg = stats + side * 4096 + b * 512;
  __shared__ float Xs[32][132];
  const int t = threadIdx.x;
  const int s = t >> 1, half = t & 1;
  for(int cc = 0; cc < 512; cc += 32){
    __syncthreads();
    #pragma unroll
    for(int u = 0; u < 4; u++){
      int q = t + u * 256;
      int row = q >> 5, f4 = q & 31;
      float4 v = *(const float4*)(Xb + (size_t)(cc + row) * 4096 + s0 + f4 * 4);
      *(float4*)(&Xs[row][f4 * 4]) = v;
    }
    __syncthreads();
    f16x8 h0, h1, l0, l1;
    #pragma unroll
    for(int i = 0; i < 8; i++){
      float x = Xs[half * 16 + i][s];
      f16 h = (f16)x; h0[i] = h; l0[i] = (f16)(x - (float)h);
    }
    #pragma unroll
    for(int i = 0; i < 8; i++){
      float x = Xs[half * 16 + 8 + i][s];
      f16 h = (f16)x; h1[i] = h; l1[i] = (f16)(x - (float)h);
    }
    size_t o = (size_t)(s0 + s) * 512 + cc + half * 16;
    *(f16x8*)(Oh + o) = h0; *(f16x8*)(Oh + o + 8) = h1;
    *(f16x8*)(Ol + o) = l0; *(f16x8*)(Ol + o + 8) = l1;
    // fused MVN partial sums: 32 c-rows x 128 s from Xs
    {
      const int cl = t >> 3, part = t & 7;
      float s1 = 0.f, s2 = 0.f;
      #pragma unroll
      for(int i = 0; i < 16; i++){
        float xv = Xs[cl][part * 16 + i];
        s1 += xv; s2 += xv * xv;
      }
      s1 += __shfl_xor(s1, 1); s1 += __shfl_xor(s1, 2); s1 += __shfl_xor(s1, 4);
      s2 += __shfl_xor(s2, 1); s2 += __shfl_xor(s2, 2); s2 += __shfl_xor(s2, 4);
      if(part == 0){
        atomicAdd(Sg + cc + cl, s1);
        atomicAdd(Sg + 2048 + cc + cl, s2);
      }
    }
  }
}

// ============ 4. conv1x1 GEMM, 128o x 256s tile, dbuf glds + counted vmcnt ============
__global__ __launch_bounds__(256) void k_convT(
    const f16* __restrict__ Xt, const f16* __restrict__ Wp,
    const float* __restrict__ bias, int bw, f16* __restrict__ Out)
{
  const int b = blockIdx.z;
  const int o0 = blockIdx.y * 128;
  const int s0 = blockIdx.x * 256;
  const f16* Xb = Xt + (size_t)b * 4096 * 512;
  const f16* Wb = Wp + (bw ? (size_t)b * 262144 : 0);
  const float* bp = bias + (bw ? b * 512 : 0);
  f16* Ob = Out + (size_t)b * 512 * 4096;
  __shared__ f16 As[2][4096];   // [128][32]
  __shared__ f16 Bs[2][8192];   // [256][32]
  const int t = threadIdx.x;
  const int lane = t & 63, wid = t >> 6;
  const int wm = (wid >> 1) * 64, wn = (wid & 1) * 128;
  const int lr = lane & 15, lg = lane >> 4;
  const int sr = lane >> 2, sc = lane & 3;
  auto STAGE = [&](int d, int kk){
    #pragma unroll
    for(int i = 0; i < 2; i++){
      int r0 = wid * 32 + i * 16;
      int rr = r0 + sr;
      int cs = (sc ^ ((rr >> 1) & 3)) << 3;
      glds16(Wb + (size_t)(o0 + rr) * 512 + kk + cs, As[d] + r0 * 32);
    }
    #pragma unroll
    for(int i = 0; i < 4; i++){
      int r0 = wid * 64 + i * 16;
      int rr = r0 + sr;
      int cs = (sc ^ ((rr >> 1) & 3)) << 3;
      glds16(Xb + (size_t)(s0 + rr) * 512 + kk + cs, Bs[d] + r0 * 32);
    }
  };
  f32x4 acc[4][8] = {};
  STAGE(0, 0);
  int db = 0;
  for(int tt = 0; tt < 16; tt++){
    if(tt < 15){
      STAGE(db ^ 1, (tt + 1) * 32);
      asm volatile("s_waitcnt vmcnt(6)" ::: "memory");
    } else {
      asm volatile("s_waitcnt vmcnt(0)" ::: "memory");
    }
    barrier_f();
    f16x8 av[4], bv[8];
    #pragma unroll
    for(int mi = 0; mi < 4; mi++){
      int row = wm + mi * 16 + lr;
      av[mi] = *(const f16x8*)(As[db] + row * 32 + ((lg ^ ((row >> 1) & 3)) << 3));
    }
    #pragma unroll
    for(int ni = 0; ni < 8; ni++){
      int row = wn + ni * 16 + lr;
      bv[ni] = *(const f16x8*)(Bs[db] + row * 32 + ((lg ^ ((row >> 1) & 3)) << 3));
    }
    #pragma unroll
    for(int mi = 0; mi < 4; mi++){
      #pragma unroll
      for(int ni = 0; ni < 8; ni++)
        acc[mi][ni] = mfma16(av[mi], bv[ni], acc[mi][ni]);
    }
    barrier_f();
    db ^= 1;
  }
  #pragma unroll
  for(int mi = 0; mi < 4; mi++){
    #pragma unroll
    for(int ni = 0; ni < 8; ni++){
      #pragma unroll
      for(int j = 0; j < 4; j++){
        int o = o0 + wm + mi * 16 + lg * 4 + j;
        int s = s0 + wn + ni * 16 + lr;
        Ob[(size_t)o * 4096 + s] = (f16)(acc[mi][ni][j] + bp[o]);
      }
    }
  }
}

// ============ 4b. fused 3-output style conv, 128x256 tile ============
__global__ __launch_bounds__(256) void k_conv3out(
    const f16* __restrict__ Xt,
    const f16* __restrict__ Wk, const f16* __restrict__ Wv, const f16* __restrict__ Wv2,
    const float* __restrict__ biasp,
    f16* __restrict__ Ok, f16* __restrict__ Ov, f16* __restrict__ Ov2)
{
  const int b = blockIdx.z;
  const int seg = blockIdx.y >> 2;
  const int o0 = (blockIdx.y & 3) * 128;
  const int s0 = blockIdx.x * 256;
  const f16* Xb = Xt + (size_t)b * 4096 * 512;
  const f16* Wb = seg == 0 ? Wk + (size_t)b * 262144 : (seg == 1 ? Wv : Wv2);
  const float* bp = biasp + (seg == 0 ? 1 * 2048 + b * 512 : (seg == 1 ? 2 * 2048 : 3 * 2048));
  f16* Ob = (seg == 0 ? Ok : (seg == 1 ? Ov : Ov2)) + (size_t)b * 512 * 4096;
  __shared__ f16 As[2][4096];
  __shared__ f16 Bs[2][8192];
  const int t = threadIdx.x;
  const int lane = t & 63, wid = t >> 6;
  const int wm = (wid >> 1) * 64, wn = (wid & 1) * 128;
  const int lr = lane & 15, lg = lane >> 4;
  const int sr = lane >> 2, sc = lane & 3;
  auto STAGE = [&](int d, int kk){
    #pragma unroll
    for(int i = 0; i < 2; i++){
      int r0 = wid * 32 + i * 16;
      int rr = r0 + sr;
      int cs = (sc ^ ((rr >> 1) & 3)) << 3;
      glds16(Wb + (size_t)(o0 + rr) * 512 + kk + cs, As[d] + r0 * 32);
    }
    #pragma unroll
    for(int i = 0; i < 4; i++){
      int r0 = wid * 64 + i * 16;
      int rr = r0 + sr;
      int cs = (sc ^ ((rr >> 1) & 3)) << 3;
      glds16(Xb + (size_t)(s0 + rr) * 512 + kk + cs, Bs[d] + r0 * 32);
    }
  };
  f32x4 acc[4][8] = {};
  STAGE(0, 0);
  int db = 0;
  for(int tt = 0; tt < 16; tt++){
    if(tt < 15){
      STAGE(db ^ 1, (tt + 1) * 32);
      asm volatile("s_waitcnt vmcnt(6)" ::: "memory");
    } else {
      asm volatile("s_waitcnt vmcnt(0)" ::: "memory");
    }
    barrier_f();
    f16x8 av[4], bv[8];
    #pragma unroll
    for(int mi = 0; mi < 4; mi++){
      int row = wm + mi * 16 + lr;
      av[mi] = *(const f16x8*)(As[db] + row * 32 + ((lg ^ ((row >> 1) & 3)) << 3));
    }
    #pragma unroll
    for(int ni = 0; ni < 8; ni++){
      int row = wn + ni * 16 + lr;
      bv[ni] = *(const f16x8*)(Bs[db] + row * 32 + ((lg ^ ((row >> 1) & 3)) << 3));
    }
    #pragma unroll
    for(int mi = 0; mi < 4; mi++){
      #pragma unroll
      for(int ni = 0; ni < 8; ni++)
        acc[mi][ni] = mfma16(av[mi], bv[ni], acc[mi][ni]);
    }
    barrier_f();
    db ^= 1;
  }
  #pragma unroll
  for(int mi = 0; mi < 4; mi++){
    #pragma unroll
    for(int ni = 0; ni < 8; ni++){
      #pragma unroll
      for(int j = 0; j < 4; j++){
        int o = o0 + wm + mi * 16 + lg * 4 + j;
        int s = s0 + wn + ni * 16 + lr;
        Ob[(size_t)o * 4096 + s] = (f16)(acc[mi][ni][j] + bp[o]);
      }
    }
  }
}

// ============ 5. PA1 (f16 path) split-K MFMA ============
__global__ __launch_bounds__(256) void k_pa1(
    const f16* __restrict__ Qh, const f16* __restrict__ Kh, float* __restrict__ pa1p)
{
  const int slice = blockIdx.x & 7;
  const int bh = blockIdx.x >> 3;
  const size_t base = (size_t)bh * 64 * 4096;
  __shared__ f16 Ah[2][64][72], Bh[2][64][72];
  const int t = threadIdx.x;
  const int lane = t & 63, wid = t >> 6;
  const int wm = (wid >> 1) * 32, wn = (wid & 1) * 32;
  const int lr = lane & 15, lg = lane >> 4;
  f32x4 acc[2][2] = {};
  for(int chunk = 0; chunk < 4; chunk++){
    const int c0 = slice * 8 + chunk * 2;
    __syncthreads();
    #pragma unroll
    for(int cc = 0; cc < 2; cc++){
      size_t cbase = base + (size_t)(c0 + cc) * 4096;
      #pragma unroll
      for(int u = 0; u < 2; u++){
        int e = u * 256 + t;
        int x = e >> 3, yh = e & 7;
        size_t src = cbase + (size_t)((x >> 3) * 512 + (x & 7) * 8 + yh * 64);
        int dst = yh * 8;
        *(f16x8*)(&Ah[cc][x][dst]) = *(const f16x8*)(Qh + src);
        *(f16x8*)(&Bh[cc][x][dst]) = *(const f16x8*)(Kh + src);
      }
    }
    __syncthreads();
    #pragma unroll
    for(int cc = 0; cc < 2; cc++){
      #pragma unroll
      for(int kc = 0; kc < 2; kc++){
        f16x8 ah[2], bh[2];
        #pragma unroll
        for(int mi = 0; mi < 2; mi++)
          ah[mi] = *(const f16x8*)(&Ah[cc][wm + mi * 16 + lr][kc * 32 + lg * 8]);
        #pragma unroll
        for(int ni = 0; ni < 2; ni++)
          bh[ni] = *(const f16x8*)(&Bh[cc][wn + ni * 16 + lr][kc * 32 + lg * 8]);
        #pragma unroll
        for(int mi = 0; mi < 2; mi++){
          #pragma unroll
          for(int ni = 0; ni < 2; ni++)
            acc[mi][ni] = mfma16(ah[mi], bh[ni], acc[mi][ni]);
        }
      }
    }
  }
  float* outp = pa1p + ((size_t)bh * 8 + slice) * 4096;
  #pragma unroll
  for(int mi = 0; mi < 2; mi++){
    #pragma unroll
    for(int ni = 0; ni < 2; ni++){
      #pragma unroll
      for(int j = 0; j < 4; j++){
        int x = wm + mi * 16 + lg * 4 + j;
        int z = wn + ni * 16 + lr;
        outp[x * 64 + z] = acc[mi][ni][j];
      }
    }
  }
}

// ============ 5b. reduce partials + argmax + near-tie flag ============
__global__ __launch_bounds__(64) void k_pa1r(
    float* __restrict__ pa1p, int* __restrict__ idx, int* __restrict__ flags)
{
  const int bh = blockIdx.x;
  const int x = threadIdx.x;
  float* p = pa1p + (size_t)bh * 8 * 4096 + x * 64;
  float m1 = -3e38f, m2 = -3e38f; int i1 = 0;
  for(int z = 0; z < 64; z += 4){
    float4 v = *(const float4*)(p + z);
    #pragma unroll
    for(int sl = 1; sl < 8; sl++){
      float4 w = *(const float4*)(p + sl * 4096 + z);
      v.x += w.x; v.y += w.y; v.z += w.z; v.w += w.w;
    }
    *(float4*)(p + z) = v;
    float vv[4] = {v.x, v.y, v.z, v.w};
    #pragma unroll
    for(int k = 0; k < 4; k++){
      if(vv[k] > m1){ m2 = m1; m1 = vv[k]; i1 = z + k; }
      else if(vv[k] > m2){ m2 = vv[k]; }
    }
  }
  idx[bh * 64 + x] = i1;
  flags[bh * 64 + x] = (m2 >= m1 - 0.5f) ? 1 : 0;
}

// ============ 5c. exact refinement for near-tie argmax rows (pipelined gemm) ============
__global__ __launch_bounds__(256) void k_refine(
    const f16* __restrict__ Xqh, const f16* __restrict__ Xql,
    const f16* __restrict__ Xkh, const f16* __restrict__ Xkl,
    const f16* __restrict__ Wqh, const f16* __restrict__ Wql,
    const f16* __restrict__ Wkh, const f16* __restrict__ Wkl,
    const float* __restrict__ biasp, const float* __restrict__ pa1p,
    const int* __restrict__ flags, int* __restrict__ idx)
{
  const int bid = blockIdx.x;
  if(flags[bid] == 0) return;
  const int bh = bid >> 6, x = bid & 63;
  const int b = bh >> 3, hd = bh & 7;
  __shared__ __align__(16) f16 Ah[64][72], Al[64][72], Bh[64][72], Bl[64][72];
  __shared__ float q2s[64][65];
  __shared__ float red[4];
  __shared__ float vals[64];
  __shared__ int cand[64];
  const int t = threadIdx.x;
  const int lane = t & 63, wid = t >> 6;
  const int wm = (wid >> 1) * 32, wn = (wid & 1) * 32;
  const int lr = lane & 15, lg = lane >> 4;
  const int srw = t >> 2, soc = (t & 3) * 2;

  auto gemm = [&](const f16* Wh_, const f16* Wl_, const f16* Xh_, const f16* Xl_,
                  int blk, f32x4 (&acc)[2][2]){
    const size_t wrow = ((size_t)(b * 512 + hd * 64 + srw)) * 512 + soc * 8;
    const int s = (blk >> 3) * 512 + (blk & 7) * 8 + (srw >> 3) * 64 + (srw & 7);
    const size_t xrow = ((size_t)b * 4096 + s) * 512 + soc * 8;
    f16x8 r0, r1, r2, r3, r4, r5, r6, r7;
    #define RLOAD(ch, a0,a1,a2,a3,a4,a5,a6,a7) do{            \
      a0 = *(const f16x8*)(Wh_ + wrow + (ch) * 64);           \
      a1 = *(const f16x8*)(Wh_ + wrow + (ch) * 64 + 8);       \
      a2 = *(const f16x8*)(Wl_ + wrow + (ch) * 64);           \
      a3 = *(const f16x8*)(Wl_ + wrow + (ch) * 64 + 8);       \
      a4 = *(const f16x8*)(Xh_ + xrow + (ch) * 64);           \
      a5 = *(const f16x8*)(Xh_ + xrow + (ch) * 64 + 8);       \
      a6 = *(const f16x8*)(Xl_ + xrow + (ch) * 64);           \
      a7 = *(const f16x8*)(Xl_ + xrow + (ch) * 64 + 8);       \
    }while(0)
    RLOAD(0, r0,r1,r2,r3,r4,r5,r6,r7);
    #pragma unroll
    for(int ch = 0; ch < 8; ch++){
      __syncthreads();
      *(f16x8*)(&Ah[srw][soc * 8])     = r0;
      *(f16x8*)(&Ah[srw][soc * 8 + 8]) = r1;
      *(f16x8*)(&Al[srw][soc * 8])     = r2;
      *(f16x8*)(&Al[srw][soc * 8 + 8]) = r3;
      *(f16x8*)(&Bh[srw][soc * 8])     = r4;
      *(f16x8*)(&Bh[srw][soc * 8 + 8]) = r5;
      *(f16x8*)(&Bl[srw][soc * 8])     = r6;
      *(f16x8*)(&Bl[srw][soc * 8 + 8]) = r7;
      f16x8 n0, n1, n2, n3, n4, n5, n6, n7;
      if(ch < 7) RLOAD(ch + 1, n0,n1,n2,n3,n4,n5,n6,n7);
      __syncthreads();
      #pragma unroll
      for(int kc = 0; kc < 2; kc++){
        f16x8 ah[2], al[2], bh2[2], bl2[2];
        #pragma unroll
        for(int mi = 0; mi < 2; mi++){
          int row = wm + mi * 16 + lr;
          ah[mi] = *(const f16x8*)(&Ah[row][kc * 32 + lg * 8]);
          al[mi] = *(const f16x8*)(&Al[row][kc * 32 + lg * 8]);
        }
        #pragma unroll
        for(int ni = 0; ni < 2; ni++){
          int row = wn + ni * 16 + lr;
          bh2[ni] = *(const f16x8*)(&Bh[row][kc * 32 + lg * 8]);
          bl2[ni] = *(const f16x8*)(&Bl[row][kc * 32 + lg * 8]);
        }
        #pragma unroll
        for(int mi = 0; mi < 2; mi++){
          #pragma unroll
          for(int ni = 0; ni < 2; ni++){
            f32x4 a = acc[mi][ni];
            a = mfma16(ah[mi], bh2[ni], a);
            a = mfma16(ah[mi], bl2[ni], a);
            a = mfma16(al[mi], bh2[ni], a);
            acc[mi][ni] = a;
          }
        }
      }
      r0 = n0; r1 = n1; r2 = n2; r3 = n3;
      r4 = n4; r5 = n5; r6 = n6; r7 = n7;
    }
    #undef RLOAD
  };

  if(t < 64) vals[t] = pa1p[(size_t)bh * 8 * 4096 + x * 64 + t];
  __syncthreads();
  if(t == 0){
    float m1 = vals[0];
    for(int z = 1; z < 64; z++) m1 = fmaxf(m1, vals[z]);
    red[0] = m1;
  }
  __syncthreads();
  const float m1 = red[0];
  if(t < 64) cand[t] = (vals[t] >= m1 - 0.5f) ? 1 : 0;
  __syncthreads();

  {
    f32x4 qa[2][2] = {};
    gemm(Wqh, Wql, Xqh, Xql, x, qa);
    #pragma unroll
    for(int mi = 0; mi < 2; mi++){
      #pragma unroll
      for(int ni = 0; ni < 2; ni++){
        #pragma unroll
        for(int j = 0; j < 4; j++){
          int c = wm + mi * 16 + lg * 4 + j;
          int y = wn + ni * 16 + lr;
          q2s[c][y] = qa[mi][ni][j] + biasp[4 * 2048 + b * 512 + hd * 64 + c];
        }
      }
    }
  }
  __syncthreads();

  float bestv = -3e38f; int besti = 0;
  for(int z = 0; z < 64; z++){
    if(!cand[z]) continue;
    f32x4 ka[2][2] = {};
    gemm(Wkh, Wkl, Xkh, Xkl, z, ka);
    float part = 0.f;
    #pragma unroll
    for(int mi = 0; mi < 2; mi++){
      #pragma unroll
      for(int ni = 0; ni < 2; ni++){
        #pragma unroll
        for(int j = 0; j < 4; j++){
          int c = wm + mi * 16 + lg * 4 + j;
          int y = wn + ni * 16 + lr;
          part += (ka[mi][ni][j] + biasp[5 * 2048 + b * 512 + hd * 64 + c]) * q2s[c][y];
        }
      }
    }
    #pragma unroll
    for(int off = 32; off > 0; off >>= 1) part += __shfl_xor(part, off);
    __syncthreads();
    if(lane == 0) red[wid] = part;
    __syncthreads();
    float pv = red[0] + red[1] + red[2] + red[3];
    if(pv > bestv){ bestv = pv; besti = z; }
  }
  if(t == 0) idx[bid] = besti;
}

// ============ 6. DA aggregation — XCD-grouped ============
__global__ __launch_bounds__(256) void k_da1(
    const f16* __restrict__ K, const f16* __restrict__ V,
    const float* __restrict__ alpha_p, const float* __restrict__ beta_p,
    float* __restrict__ kagg, float* __restrict__ vagg)
{
  const int hw = blockIdx.x;
  const int xcd = hw & 7, i = hw >> 3;
  const int g = xcd * 32 + (i >> 3);
  const int bh = g >> 3;
  const int x  = (g & 7) * 8 + (i & 7);
  const f16* Kb = K + (size_t)bh * 64 * 4096;
  const f16* Vb = V + (size_t)bh * 64 * 4096;
  __shared__ float kl[64][65];
  __shared__ float vl[64][65];
  __shared__ float kc[64], vc[64], simv[64];
  const int t = threadIdx.x;
  const int c = t >> 2, yp = t & 3;
  const int xb = (x >> 3) * 512 + (x & 7) * 8;
  #pragma unroll
  for(int u = 0; u < 2; u++){
    int yh = yp * 2 + u;
    f16x8 k8 = *(const f16x8*)(Kb + (size_t)c * 4096 + xb + yh * 64);
    f16x8 v8 = *(const f16x8*)(Vb + (size_t)c * 4096 + xb + yh * 64);
    #pragma unroll
    for(int j = 0; j < 8; j++){
      kl[c][yh * 8 + j] = (float)k8[j];
      vl[c][yh * 8 + j] = (float)v8[j];
    }
  }
  __syncthreads();
  float sk = 0.f, sv = 0.f;
  for(int yy = yp * 16; yy < yp * 16 + 16; yy++){ sk += kl[c][yy]; sv += vl[c][yy]; }
  sk += __shfl_xor(sk, 1); sk += __shfl_xor(sk, 2);
  sv += __shfl_xor(sv, 1); sv += __shfl_xor(sv, 2);
  if(yp == 0){ kc[c] = sk * (1.f / 64.f); vc[c] = sv * (1.f / 64.f); }
  __syncthreads();
  const int y = t >> 2, cp = t & 3;
  float d = 0.f;
  for(int cc = cp * 16; cc < cp * 16 + 16; cc++) d += kc[cc] * kl[cc][y];
  d += __shfl_xor(d, 1); d += __shfl_xor(d, 2);
  if(cp == 0) simv[y] = 1.f / (1.f + expf(-(beta_p[0] + alpha_p[0] * d)));
  __syncthreads();
  float ak = 0.f, av = 0.f;
  for(int yy = yp * 16; yy < yp * 16 + 16; yy++){
    float sm = simv[yy];
    ak += sm * kl[c][yy]; av += sm * vl[c][yy];
  }
  ak += __shfl_xor(ak, 1); ak += __shfl_xor(ak, 2);
  av += __shfl_xor(av, 1); av += __shfl_xor(av, 2);
  if(yp == 0){
    size_t o = ((size_t)bh * 64 + x) * 64 + c;
    kagg[o] = (ak + kc[c]) * (1.f / 65.f);
    vagg[o] = (av + vc[c]) * (1.f / 65.f);
  }
}

// ============ 7. DA attention MFMA; output TRANSPOSED [s][c] ============
__global__ __launch_bounds__(256) void k_da2(
    const f16* __restrict__ Q, const float* __restrict__ kagg,
    const float* __restrict__ vagg, f16* __restrict__ OutT)
{
  const int bh = blockIdx.x >> 4;
  const int s0 = (blockIdx.x & 15) << 8;
  const int b_ = bh >> 3, hd = bh & 7;
  const f16* Qb = Q + (size_t)bh * 64 * 4096;
  f16* Ot = OutT + (size_t)b_ * 4096 * 512 + hd * 64;

  __shared__ __align__(16) f16 Qt[256][72];
  __shared__ __align__(16) f16 Kt[64][72];
  __shared__ __align__(16) f16 Vt[64][72];
  const int t = threadIdx.x;
  const int lane = t & 63, w = t >> 6;
  const int lr = lane & 15, lg = lane >> 4;

  {
    const int so = t & 31;
    #pragma unroll
    for(int pass = 0; pass < 8; pass++){
      int c = (t >> 5) + pass * 8;
      f16x8 q8 = *(const f16x8*)(Qb + (size_t)c * 4096 + s0 + so * 8);
      #pragma unroll
      for(int j = 0; j < 8; j++){
        int s = so * 8 + j;
        int col = (((c >> 3) ^ (s & 7)) << 3) | (c & 7);
        Qt[s][col] = q8[j];
      }
    }
  }
  {
    const int z = t >> 2, c0 = (t & 3) * 16;
    #pragma unroll
    for(int u = 0; u < 4; u++){
      float4 v = *(const float4*)(kagg + (size_t)bh * 4096 + z * 64 + c0 + u * 4);
      float vv[4] = {v.x, v.y, v.z, v.w};
      #pragma unroll
      for(int j = 0; j < 4; j++){
        int c = c0 + u * 4 + j;
        int col = (((c >> 3) ^ (z & 7)) << 3) | (c & 7);
        Kt[z][col] = (f16)vv[j];
      }
    }
    #pragma unroll
    for(int u = 0; u < 4; u++){
      float4 v = *(const float4*)(vagg + (size_t)bh * 4096 + z * 64 + c0 + u * 4);
      float vv[4] = {v.x, v.y, v.z, v.w};
      #pragma unroll
      for(int j = 0; j < 4; j++){
        int c = c0 + u * 4 + j;
        int col = (((z >> 3) ^ (c & 7)) << 3) | (z & 7);
        Vt[c][col] = (f16)vv[j];
      }
    }
  }
  __syncthreads();

  f32x4 acc[4][4] = {};
  #pragma unroll
  for(int kc = 0; kc < 2; kc++){
    f16x8 af[4], bf[4];
    #pragma unroll
    for(int mi = 0; mi < 4; mi++){
      int row = w * 64 + mi * 16 + lr;
      af[mi] = *(const f16x8*)(&Qt[row][(((kc * 4 + lg) ^ (row & 7)) << 3)]);
    }
    #pragma unroll
    for(int ni = 0; ni < 4; ni++){
      int row = ni * 16 + lr;
      bf[ni] = *(const f16x8*)(&Kt[row][(((kc * 4 + lg) ^ (row & 7)) << 3)]);
    }
    #pragma unroll
    for(int mi = 0; mi < 4; mi++){
      #pragma unroll
      for(int ni = 0; ni < 4; ni++)
        acc[mi][ni] = mfma16(af[mi], bf[ni], acc[mi][ni]);
    }
  }

  #pragma unroll
  for(int mi = 0; mi < 4; mi++){
    #pragma unroll
    for(int j = 0; j < 4; j++){
      float v0 = acc[mi][0][j], v1 = acc[mi][1][j], v2 = acc[mi][2][j], v3 = acc[mi][3][j];
      float m = fmaxf(fmaxf(v0, v1), fmaxf(v2, v3));
      m = fmaxf(m, __shfl_xor(m, 1)); m = fmaxf(m, __shfl_xor(m, 2));
      m = fmaxf(m, __shfl_xor(m, 4)); m = fmaxf(m, __shfl_xor(m, 8));
      float e0 = expf(v0 - m), e1 = expf(v1 - m), e2 = expf(v2 - m), e3 = expf(v3 - m);
      float sm = e0 + e1 + e2 + e3;
      sm += __shfl_xor(sm, 1); sm += __shfl_xor(sm, 2);
      sm += __shfl_xor(sm, 4); sm += __shfl_xor(sm, 8);
      float inv = 1.f / sm;
      float ev[4] = {e0, e1, e2, e3};
      int row = w * 64 + mi * 16 + lg * 4 + j;
      #pragma unroll
      for(int ni = 0; ni < 4; ni++){
        int z = lr + 16 * ni;
        int col = (((z >> 3) ^ (row & 7)) << 3) | (z & 7);
        Qt[row][col] = (f16)(ev[ni] * inv);
      }
    }
  }

  f32x4 acc2[4][4] = {};
  #pragma unroll
  for(int kc = 0; kc < 2; kc++){
    f16x8 af[4], bf[4];
    #pragma unroll
    for(int mi = 0; mi < 4; mi++){
      int row = w * 64 + mi * 16 + lr;
      af[mi] = *(const f16x8*)(&Qt[row][(((kc * 4 + lg) ^ (row & 7)) << 3)]);
    }
    #pragma unroll
    for(int ni = 0; ni < 4; ni++){
      int row = ni * 16 + lr;
      bf[ni] = *(const f16x8*)(&Vt[row][(((kc * 4 + lg) ^ (row & 7)) << 3)]);
    }
    #pragma unroll
    for(int mi = 0; mi < 4; mi++){
      #pragma unroll
      for(int ni = 0; ni < 4; ni++)
        acc2[mi][ni] = mfma16(af[mi], bf[ni], acc2[mi][ni]);
    }
  }

  #pragma unroll
  for(int mi = 0; mi < 4; mi++){
    #pragma unroll
    for(int j = 0; j < 4; j++){
      size_t srow = (size_t)(s0 + w * 64 + mi * 16 + lg * 4 + j) * 512;
      #pragma unroll
      for(int ni = 0; ni < 4; ni++)
        Ot[srow + ni * 16 + lr] = (f16)acc2[mi][ni][j];
    }
  }
}

// ============ 9. PA intra-block attention; output TRANSPOSED [s][c] ============
__global__ __launch_bounds__(256) void k_pa2(
    const f16* __restrict__ Qh, const f16* __restrict__ Kh,
    const f16* __restrict__ V2, const int* __restrict__ idx, f16* __restrict__ OutT)
{
  const int hw = blockIdx.x;
  const int bh = (hw & 7) * 4 + ((hw >> 3) >> 6);
  const int x  = (hw >> 3) & 63;
  const int b_ = bh >> 3, hd = bh & 7;
  const size_t base = (size_t)bh * 64 * 4096;
  f16* Ot = OutT + (size_t)b_ * 4096 * 512 + hd * 64;

  __shared__ __align__(16) char Ubuf[18432];
  __shared__ f16 Vn[64][72];
  __shared__ f16 Ps[64][72];
  f16   (*Qt)[72] = (f16(*)[72])Ubuf;
  f16   (*Kt)[72] = (f16(*)[72])(Ubuf + 9216);
  float (*Lf)[66] = (float(*)[66])Ubuf;
  float (*Os)[67] = (float(*)[67])Ubuf;

  const int t = threadIdx.x;
  const int lane = t & 63, wid = t >> 6;
  const int wm = (wid >> 1) * 32, wn = (wid & 1) * 32;
  const int lr = lane & 15, lg = lane >> 4;

  const int xk = idx[bh * 64 + x];
  const int xb = (x >> 3) * 512 + (x & 7) * 8;
  const int kb = (xk >> 3) * 512 + (xk & 7) * 8;

  {
    const int c = t >> 2, q4 = t & 3;
    #pragma unroll
    for(int u = 0; u < 2; u++){
      int yh = q4 * 2 + u;
      f16x8 q8 = *(const f16x8*)(Qh + base + (size_t)c * 4096 + xb + yh * 64);
      f16x8 k8 = *(const f16x8*)(Kh + base + (size_t)c * 4096 + kb + yh * 64);
      f16x8 v8 = *(const f16x8*)(V2 + base + (size_t)c * 4096 + kb + yh * 64);
      int col = ((((c >> 3) ^ yh) & 7) << 3) + (c & 7);
      #pragma unroll
      for(int j = 0; j < 8; j++){
        Qt[yh * 8 + j][col] = q8[j];
        Kt[yh * 8 + j][col] = k8[j];
      }
      *(f16x8*)(&Vn[c][yh * 8]) = v8;
    }
  }
  __syncthreads();

  f32x4 acc[2][2] = {};
  #pragma unroll
  for(int kc = 0; kc < 2; kc++){
    f16x8 af[2], bf[2];
    #pragma unroll
    for(int mi = 0; mi < 2; mi++){
      int row = wm + mi * 16 + lr;
      af[mi] = *(const f16x8*)(&Qt[row][((((kc * 4 + lg) ^ (row >> 3)) & 7) << 3)]);
    }
    #pragma unroll
    for(int ni = 0; ni < 2; ni++){
      int row = wn + ni * 16 + lr;
      bf[ni] = *(const f16x8*)(&Kt[row][((((kc * 4 + lg) ^ (row >> 3)) & 7) << 3)]);
    }
    #pragma unroll
    for(int mi = 0; mi < 2; mi++){
      #pragma unroll
      for(int ni = 0; ni < 2; ni++)
        acc[mi][ni] = mfma16(af[mi], bf[ni], acc[mi][ni]);
    }
  }
  __syncthreads();
  #pragma unroll
  for(int mi = 0; mi < 2; mi++){
    #pragma unroll
    for(int ni = 0; ni < 2; ni++){
      #pragma unroll
      for(int j = 0; j < 4; j++)
        Lf[wm + mi * 16 + lg * 4 + j][wn + ni * 16 + lr] = acc[mi][ni][j];
    }
  }
  __syncthreads();

  {
    const int y = t >> 2, zp = t & 3;
    float l[16];
    #pragma unroll
    for(int i = 0; i < 16; i++) l[i] = Lf[y][zp * 16 + i];
    float m = l[0];
    #pragma unroll
    for(int i = 1; i < 16; i++) m = fmaxf(m, l[i]);
    m = fmaxf(m, __shfl_xor(m, 1)); m = fmaxf(m, __shfl_xor(m, 2));
    float sum = 0.f;
    #pragma unroll
    for(int i = 0; i < 16; i++){ l[i] = expf(l[i] - m); sum += l[i]; }
    sum += __shfl_xor(sum, 1); sum += __shfl_xor(sum, 2);
    float inv = 1.f / sum;
    f16x8 p0, p1;
    #pragma unroll
    for(int i = 0; i < 8; i++){ p0[i] = (f16)(l[i] * inv); p1[i] = (f16)(l[8 + i] * inv); }
    *(f16x8*)(&Ps[y][zp * 16]) = p0;
    *(f16x8*)(&Ps[y][zp * 16 + 8]) = p1;
  }
  __syncthreads();

  f32x4 acc2[2][2] = {};
  #pragma unroll
  for(int kc = 0; kc < 2; kc++){
    f16x8 af[2], bf[2];
    #pragma unroll
    for(int mi = 0; mi < 2; mi++)
      af[mi] = *(const f16x8*)(&Ps[wm + mi * 16 + lr][kc * 32 + lg * 8]);
    #pragma unroll
    for(int ni = 0; ni < 2; ni++)
      bf[ni] = *(const f16x8*)(&Vn[wn + ni * 16 + lr][kc * 32 + lg * 8]);
    #pragma unroll
    for(int mi = 0; mi < 2; mi++){
      #pragma unroll
      for(int ni = 0; ni < 2; ni++)
        acc2[mi][ni] = mfma16(af[mi], bf[ni], acc2[mi][ni]);
    }
  }
  #pragma unroll
  for(int mi = 0; mi < 2; mi++){
    #pragma unroll
    for(int ni = 0; ni < 2; ni++){
      #pragma unroll
      for(int j = 0; j < 4; j++)
        Os[wn + ni * 16 + lr][wm + mi * 16 + lg * 4 + j] = acc2[mi][ni][j];
    }
  }
  __syncthreads();

  {
    const int y = t >> 2, cq = (t & 3) * 16;
    size_t srow = (size_t)(xb + (y >> 3) * 64 + (y & 7)) * 512;
    f16x8 w0, w1;
    #pragma unroll
    for(int i = 0; i < 8; i++){ w0[i] = (f16)Os[cq + i][y]; w1[i] = (f16)Os[cq + 8 + i][y]; }
    *(f16x8*)(Ot + srow + cq) = w0;
    *(f16x8*)(Ot + srow + cq + 8) = w1;
  }
}

// ============ 10. Final: 128x256 tile, 2 passes ============
__global__ __launch_bounds__(256) void k_finalT(
    const f16* __restrict__ X1t, const f16* __restrict__ X2t,
    const f16* __restrict__ W1p, const f16* __restrict__ W2p,
    const float* __restrict__ B1, const float* __restrict__ B2,
    const float* __restrict__ content, float* __restrict__ out)
{
  const int b = blockIdx.z;
  const int o0 = blockIdx.y * 128;
  const int s0 = blockIdx.x * 256;
  __shared__ f16 As[2][4096];
  __shared__ f16 Bs[2][8192];
  const int t = threadIdx.x;
  const int lane = t & 63, wid = t >> 6;
  const int wm = (wid >> 1) * 64, wn = (wid & 1) * 128;
  const int lr = lane & 15, lg = lane >> 4;
  const int sr = lane >> 2, sc = lane & 3;
  const f16* Xp[2] = {X1t + (size_t)b * 4096 * 512, X2t + (size_t)b * 4096 * 512};
  const f16* Wq[2] = {W1p, W2p};
  auto STAGE = [&](int d, int tt){
    const f16* Xb = Xp[tt >> 4];
    const f16* Wb = Wq[tt >> 4];
    int kk = (tt & 15) * 32;
    #pragma unroll
    for(int i = 0; i < 2; i++){
      int r0 = wid * 32 + i * 16;
      int rr = r0 + sr;
      int cs = (sc ^ ((rr >> 1) & 3)) << 3;
      glds16(Wb + (size_t)(o0 + rr) * 512 + kk + cs, As[d] + r0 * 32);
    }
    #pragma unroll
    for(int i = 0; i < 4; i++){
      int r0 = wid * 64 + i * 16;
      int rr = r0 + sr;
      int cs = (sc ^ ((rr >> 1) & 3)) << 3;
      glds16(Xb + (size_t)(s0 + rr) * 512 + kk + cs, Bs[d] + r0 * 32);
    }
  };
  f32x4 acc[4][8] = {};
  STAGE(0, 0);
  int db = 0;
  for(int tt = 0; tt < 32; tt++){
    if(tt < 31){
      STAGE(db ^ 1, tt + 1);
      asm volatile("s_waitcnt vmcnt(6)" ::: "memory");
    } else {
      asm volatile("s_waitcnt vmcnt(0)" ::: "memory");
    }
    barrier_f();
    f16x8 av[4], bv[8];
    #pragma unroll
    for(int mi = 0; mi < 4; mi++){
      int row = wm + mi * 16 + lr;
      av[mi] = *(const f16x8*)(As[db] + row * 32 + ((lg ^ ((row >> 1) & 3)) << 3));
    }
    #pragma unroll
    for(int ni = 0; ni < 8; ni++){
      int row = wn + ni * 16 + lr;
      bv[ni] = *(const f16x8*)(Bs[db] + row * 32 + ((lg ^ ((row >> 1) & 3)) << 3));
    }
    #pragma unroll
    for(int mi = 0; mi < 4; mi++){
      #pragma unroll
      for(int ni = 0; ni < 8; ni++)
        acc[mi][ni] = mfma16(av[mi], bv[ni], acc[mi][ni]);
    }
    barrier_f();
    db ^= 1;
  }
  #pragma unroll
  for(int mi = 0; mi < 4; mi++){
    #pragma unroll
    for(int ni = 0; ni < 8; ni++){
      #pragma unroll
      for(int j = 0; j < 4; j++){
        int o = o0 + wm + mi * 16 + lg * 4 + j;
        int s = s0 + wn + ni * 16 + lr;
        size_t gi = ((size_t)b * 512 + o) * 4096 + s;
        out[gi] = acc[mi][ni][j] + B1[o] + B2[o] + content[gi];
      }
    }
  }
}

extern "C" void kernel_launch(void* const* d_in, const int* in_sizes, int n_in,
                              void* d_out, int out_size, void* d_ws, size_t ws_size,
                              hipStream_t stream) {
  (void)in_sizes; (void)n_in; (void)out_size; (void)ws_size;
  const float* content = (const float*)d_in[0];
  const float* style   = (const float*)d_in[1];
  const float* q_w  = (const float*)d_in[2];  const float* q_b  = (const float*)d_in[3];
  const float* k_w  = (const float*)d_in[4];  const float* k_b  = (const float*)d_in[5];
  const float* v_w  = (const float*)d_in[6];  const float* v_b  = (const float*)d_in[7];
  const float* q2_w = (const float*)d_in[8];  const float* q2_b = (const float*)d_in[9];
  const float* k2_w = (const float*)d_in[10]; const float* k2_b = (const float*)d_in[11];
  const float* v2_w = (const float*)d_in[12]; const float* v2_b = (const float*)d_in[13];
  const float* f1_w = (const float*)d_in[14]; const float* f1_b = (const float*)d_in[15];
  const float* f2_w = (const float*)d_in[16]; const float* f2_b = (const float*)d_in[17];
  const float* sim_alpha = (const float*)d_in[18];
  const float* sim_beta  = (const float*)d_in[19];

  char* ws = (char*)d_ws;
  #define SLOT(i) (ws + (size_t)(i) * 16777216)
  f16* cth = (f16*)SLOT(0);
  f16* ctl = (f16*)SLOT(1);
  f16* sth = (f16*)SLOT(2);
  f16* stl = (f16*)SLOT(3);
  f16* wbase = (f16*)SLOT(4);
  f16* qw   = wbase;
  f16* kw   = wbase + 1 * 1048576;
  f16* q2wh = wbase + 2 * 1048576;
  f16* q2wl = wbase + 3 * 1048576;
  f16* k2wh = wbase + 4 * 1048576;
  f16* k2wl = wbase + 5 * 1048576;
  f16* vw   = wbase + 6 * 1048576;
  f16* v2w  = vw + 262144;
  f16* f1w  = vw + 524288;
  f16* f2w  = vw + 786432;
  f16*   q2h   = (f16*)SLOT(5);
  f16*   k2h   = (f16*)SLOT(6);
  float* pa1p  = (float*)SLOT(7);
  int*   flags = (int*)(ws + 7 * 16777216 + 8388608);
  f16*   qbuf  = (f16*)SLOT(3);      // stl dead after refine
  f16*   kbuf  = (f16*)SLOT(0);      // cth dead after convT(q)
  f16*   vbuf  = (f16*)SLOT(1);      // ctl dead after refine
  f16*   v2buf = (f16*)SLOT(7);      // pa1p/flags dead after refine
  f16*   da_t  = (f16*)SLOT(2);      // sth dead after conv3out
  f16*   pa_t  = (f16*)SLOT(3);      // qbuf dead after da2
  float* stats = (float*)(ws + 134217728);
  float* biasp = (float*)(ws + 134217728 + 32768);
  float* kagg  = (float*)(ws + 134217728 + 32768);
  float* vagg  = (float*)(ws + 134217728 + 557056);
  int*   idxb  = (int*)(ws + 134217728 + 1081344);

  dim3 gconv(16, 4, 4);

  // zero raw-moment accumulators (S/SS), then prep_x accumulates them
  hipMemsetAsync(stats, 0, 32768, stream);

  k_prep_x<<<dim3(32,4,2), 256, 0, stream>>>(content, style, cth, ctl, sth, stl, stats);

  k_prep_w_all<<<320, 256, 0, stream>>>(
      q_w, q_b, k_w, k_b, q2_w, q2_b, k2_w, k2_b,
      v_w, v_b, v2_w, v2_b, f1_w, f2_w, stats,
      qw, kw, q2wh, q2wl, k2wh, k2wl, vw, v2w, f1w, f2w, biasp);

  // q2/k2 projections in plain f16 (argmax near-ties repaired by k_refine)
  k_convT<<<gconv, 256, 0, stream>>>(cth, q2wh, biasp + 4 * 2048, 1, q2h);
  k_convT<<<gconv, 256, 0, stream>>>(sth, k2wh, biasp + 5 * 2048, 1, k2h);
  k_pa1<<<256, 256, 0, stream>>>(q2h, k2h, pa1p);
  k_pa1r<<<32, 64, 0, stream>>>(pa1p, idxb, flags);
  k_refine<<<2048, 256, 0, stream>>>(cth, ctl, sth, stl,
                                     q2wh, q2wl, k2wh, k2wl,
                                     biasp, pa1p, flags, idxb);

  k_convT<<<gconv, 256, 0, stream>>>(cth, qw, biasp + 0 * 2048, 1, qbuf);
  k_conv3out<<<dim3(16,12,4), 256, 0, stream>>>(sth, kw, vw, v2w, biasp,
                                                kbuf, vbuf, v2buf);

  k_da1<<<2048, 256, 0, stream>>>(kbuf, vbuf, sim_alpha, sim_beta, kagg, vagg);
  k_da2<<<512, 256, 0, stream>>>(qbuf, kagg, vagg, da_t);
  k_pa2<<<2048, 256, 0, stream>>>(q2h, k2h, v2buf, idxb, pa_t);

  k_finalT<<<gconv, 256, 0, stream>>>(da_t, pa_t, f1w, f2w, f1_b, f2_b,
                                      content, (float*)d_out);
}

// Round 14
// 304.609 us; speedup vs baseline: 1.1089x; 1.1089x over previous
//
#include <hip/hip_runtime.h>

typedef unsigned short u16;
typedef unsigned int   u32;
typedef _Float16       f16;

typedef f16   f16x8 __attribute__((ext_vector_type(8)));
typedef f16   f16x4 __attribute__((ext_vector_type(4)));
typedef float f32x4 __attribute__((ext_vector_type(4)));

__device__ __forceinline__ f32x4 mfma16(f16x8 a, f16x8 b, f32x4 c){
  return __builtin_amdgcn_mfma_f32_16x16x32_f16(a, b, c, 0, 0, 0);
}

// async global->LDS, 16B per lane; LDS dest = wave-uniform base + lane*16 (linear)
__device__ __forceinline__ void glds16(const f16* g, f16* l){
  __builtin_amdgcn_global_load_lds(
      (const __attribute__((address_space(1))) void*)g,
      (__attribute__((address_space(3))) void*)l, 16, 0, 0);
}

__device__ __forceinline__ void barrier_f(){
  __builtin_amdgcn_s_barrier();
  asm volatile("" ::: "memory");
}

// ============ 2. ALL weight preps: mean/rstd computed from raw S/SS sums ============
__global__ __launch_bounds__(256) void k_prep_w_all(
    const float* __restrict__ qW,  const float* __restrict__ qB,
    const float* __restrict__ kW,  const float* __restrict__ kB,
    const float* __restrict__ q2W, const float* __restrict__ q2B,
    const float* __restrict__ k2W, const float* __restrict__ k2B,
    const float* __restrict__ vW,  const float* __restrict__ vB,
    const float* __restrict__ v2W, const float* __restrict__ v2B,
    const float* __restrict__ f1W, const float* __restrict__ f2W,
    const float* __restrict__ stats,
    f16* __restrict__ qw, f16* __restrict__ kw,
    f16* __restrict__ q2wh, f16* __restrict__ q2wl,
    f16* __restrict__ k2wh, f16* __restrict__ k2wl,
    f16* __restrict__ vw, f16* __restrict__ v2w,
    f16* __restrict__ f1w, f16* __restrict__ f2w,
    float* __restrict__ biasp)
{
  const int t = threadIdx.x;
  int rid = blockIdx.x * 32 + (t >> 3);
  const float *W; const float *B = nullptr;
  int side = -1, b = 0, o;
  f16 *oh; f16 *ol = nullptr; float* bs = nullptr;
  if(rid < 2048){
    b = rid >> 9; o = rid & 511;
    W = qW; B = qB; side = 0;
    oh = qw + (size_t)(b * 512 + o) * 512;
    bs = biasp + 0 * 2048 + b * 512 + o;
  } else if(rid < 4096){
    rid -= 2048; b = rid >> 9; o = rid & 511;
    W = kW; B = kB; side = 1;
    oh = kw + (size_t)(b * 512 + o) * 512;
    bs = biasp + 1 * 2048 + b * 512 + o;
  } else if(rid < 6144){
    rid -= 4096; b = rid >> 9; o = rid & 511;
    W = q2W; B = q2B; side = 0;
    oh = q2wh + (size_t)(b * 512 + o) * 512;
    ol = q2wl + (size_t)(b * 512 + o) * 512;
    bs = biasp + 4 * 2048 + b * 512 + o;
  } else if(rid < 8192){
    rid -= 6144; b = rid >> 9; o = rid & 511;
    W = k2W; B = k2B; side = 1;
    oh = k2wh + (size_t)(b * 512 + o) * 512;
    ol = k2wl + (size_t)(b * 512 + o) * 512;
    bs = biasp + 5 * 2048 + b * 512 + o;
  } else if(rid < 8704){
    o = rid - 8192; W = vW; B = vB;
    oh = vw + (size_t)o * 512;
    bs = biasp + 2 * 2048 + o;
  } else if(rid < 9216){
    o = rid - 8704; W = v2W; B = v2B;
    oh = v2w + (size_t)o * 512;
    bs = biasp + 3 * 2048 + o;
  } else if(rid < 9728){
    o = rid - 9216; W = f1W;
    oh = f1w + (size_t)o * 512;
  } else {
    o = rid - 9728; W = f2W;
    oh = f2w + (size_t)o * 512;
  }
  const float* Sv  = (side >= 0) ? stats + side * 4096 + b * 512 : nullptr;
  const float* SSv = Sv ? Sv + 2048 : nullptr;
  const int c0 = (t & 7) * 64;
  float dot = 0.f;
  #pragma unroll
  for(int i = 0; i < 64; i += 8){
    int c = c0 + i;
    float w[8];
    *(float4*)(w)     = *(const float4*)(W + (size_t)o * 512 + c);
    *(float4*)(w + 4) = *(const float4*)(W + (size_t)o * 512 + c + 4);
    f16x8 h8, l8;
    #pragma unroll
    for(int j = 0; j < 8; j++){
      float wp = w[j];
      if(side >= 0){
        float S = Sv[c + j], SS = SSv[c + j];
        float mean = S * (1.f / 4096.f);
        float r = rsqrtf((SS - S * mean) * (1.f / 4095.f) + 1e-5f);
        dot += wp * mean * r;
        wp *= r;
      }
      f16 h = (f16)wp;
      h8[j] = h; l8[j] = (f16)(wp - (float)h);
    }
    *(f16x8*)(oh + c) = h8;
    if(ol) *(f16x8*)(ol + c) = l8;
  }
  if(bs){
    dot += __shfl_xor(dot, 1); dot += __shfl_xor(dot, 2); dot += __shfl_xor(dot, 4);
    if((t & 7) == 0) *bs = B[o] - dot;
  }
}

// ============ 3. X prep: transpose + f16 hi/lo split + fused MVN stats (S/SS atomics) ============
__global__ __launch_bounds__(256) void k_prep_x(
    const float* __restrict__ content, const float* __restrict__ style,
    f16* __restrict__ cth, f16* __restrict__ ctl,
    f16* __restrict__ sth, f16* __restrict__ stl,
    float* __restrict__ stats)
{
  const int side = blockIdx.z;
  const int b = blockIdx.y;
  const int s0 = blockIdx.x * 128;
  const float* Xb = (side ? style : content) + (size_t)b * 512 * 4096;
  f16* Oh = (side ? sth : cth) + (size_t)b * 4096 * 512;
  f16* Ol = (side ? stl : ctl) + (size_t)b * 4096 * 512;
  float* Sg = stats + side * 4096 + b * 512;
  __shared__ float Xs[32][132];
  const int t = threadIdx.x;
  const int s = t >> 1, half = t & 1;
  for(int cc = 0; cc < 512; cc += 32){
    __syncthreads();
    #pragma unroll
    for(int u = 0; u < 4; u++){
      int q = t + u * 256;
      int row = q >> 5, f4 = q & 31;
      float4 v = *(const float4*)(Xb + (size_t)(cc + row) * 4096 + s0 + f4 * 4);
      *(float4*)(&Xs[row][f4 * 4]) = v;
    }
    __syncthreads();
    f16x8 h0, h1, l0, l1;
    #pragma unroll
    for(int i = 0; i < 8; i++){
      float x = Xs[half * 16 + i][s];
      f16 h = (f16)x; h0[i] = h; l0[i] = (f16)(x - (float)h);
    }
    #pragma unroll
    for(int i = 0; i < 8; i++){
      float x = Xs[half * 16 + 8 + i][s];
      f16 h = (f16)x; h1[i] = h; l1[i] = (f16)(x - (float)h);
    }
    size_t o = (size_t)(s0 + s) * 512 + cc + half * 16;
    *(f16x8*)(Oh + o) = h0; *(f16x8*)(Oh + o + 8) = h1;
    *(f16x8*)(Ol + o) = l0; *(f16x8*)(Ol + o + 8) = l1;
    // fused MVN partial sums: 32 c-rows x 128 s from Xs
    {
      const int cl = t >> 3, part = t & 7;
      float s1 = 0.f, s2 = 0.f;
      #pragma unroll
      for(int i = 0; i < 16; i++){
        float xv = Xs[cl][part * 16 + i];
        s1 += xv; s2 += xv * xv;
      }
      s1 += __shfl_xor(s1, 1); s1 += __shfl_xor(s1, 2); s1 += __shfl_xor(s1, 4);
      s2 += __shfl_xor(s2, 1); s2 += __shfl_xor(s2, 2); s2 += __shfl_xor(s2, 4);
      if(part == 0){
        atomicAdd(Sg + cc + cl, s1);
        atomicAdd(Sg + 2048 + cc + cl, s2);
      }
    }
  }
}

// ============ 4. conv1x1 GEMM, 128x128 tile, dbuf glds + counted vmcnt ============
__global__ __launch_bounds__(256) void k_convT(
    const f16* __restrict__ Xt, const f16* __restrict__ Wp,
    const float* __restrict__ bias, int bw, f16* __restrict__ Out)
{
  const int b = blockIdx.z;
  const int o0 = blockIdx.y * 128;
  const int s0 = blockIdx.x * 128;
  const f16* Xb = Xt + (size_t)b * 4096 * 512;
  const f16* Wb = Wp + (bw ? (size_t)b * 262144 : 0);
  const float* bp = bias + (bw ? b * 512 : 0);
  f16* Ob = Out + (size_t)b * 512 * 4096;
  __shared__ f16 As[2][4096];
  __shared__ f16 Bs[2][4096];
  const int t = threadIdx.x;
  const int lane = t & 63, wid = t >> 6;
  const int wm = (wid >> 1) * 64, wn = (wid & 1) * 64;
  const int lr = lane & 15, lg = lane >> 4;
  const int sr = lane >> 2, sc = lane & 3;
  auto STAGE = [&](int d, int kk){
    #pragma unroll
    for(int i = 0; i < 2; i++){
      int r0 = wid * 32 + i * 16;
      int rr = r0 + sr;
      int cs = (sc ^ ((rr >> 1) & 3)) << 3;
      glds16(Wb + (size_t)(o0 + rr) * 512 + kk + cs, As[d] + r0 * 32);
      glds16(Xb + (size_t)(s0 + rr) * 512 + kk + cs, Bs[d] + r0 * 32);
    }
  };
  f32x4 acc[4][4] = {};
  STAGE(0, 0);
  int db = 0;
  for(int tt = 0; tt < 16; tt++){
    if(tt < 15){
      STAGE(db ^ 1, (tt + 1) * 32);
      asm volatile("s_waitcnt vmcnt(4)" ::: "memory");
    } else {
      asm volatile("s_waitcnt vmcnt(0)" ::: "memory");
    }
    barrier_f();
    f16x8 av[4], bv[4];
    #pragma unroll
    for(int mi = 0; mi < 4; mi++){
      int row = wm + mi * 16 + lr;
      av[mi] = *(const f16x8*)(As[db] + row * 32 + ((lg ^ ((row >> 1) & 3)) << 3));
    }
    #pragma unroll
    for(int ni = 0; ni < 4; ni++){
      int row = wn + ni * 16 + lr;
      bv[ni] = *(const f16x8*)(Bs[db] + row * 32 + ((lg ^ ((row >> 1) & 3)) << 3));
    }
    #pragma unroll
    for(int mi = 0; mi < 4; mi++){
      #pragma unroll
      for(int ni = 0; ni < 4; ni++)
        acc[mi][ni] = mfma16(av[mi], bv[ni], acc[mi][ni]);
    }
    barrier_f();
    db ^= 1;
  }
  #pragma unroll
  for(int mi = 0; mi < 4; mi++){
    #pragma unroll
    for(int ni = 0; ni < 4; ni++){
      #pragma unroll
      for(int j = 0; j < 4; j++){
        int o = o0 + wm + mi * 16 + lg * 4 + j;
        int s = s0 + wn + ni * 16 + lr;
        Ob[(size_t)o * 4096 + s] = (f16)(acc[mi][ni][j] + bp[o]);
      }
    }
  }
}

// ============ 4b. fused 3-output style conv: k (batched W), v, v2 ============
__global__ __launch_bounds__(256) void k_conv3out(
    const f16* __restrict__ Xt,
    const f16* __restrict__ Wk, const f16* __restrict__ Wv, const f16* __restrict__ Wv2,
    const float* __restrict__ biasp,
    f16* __restrict__ Ok, f16* __restrict__ Ov, f16* __restrict__ Ov2)
{
  const int b = blockIdx.z;
  const int seg = blockIdx.y >> 2;
  const int o0 = (blockIdx.y & 3) * 128;
  const int s0 = blockIdx.x * 128;
  const f16* Xb = Xt + (size_t)b * 4096 * 512;
  const f16* Wb = seg == 0 ? Wk + (size_t)b * 262144 : (seg == 1 ? Wv : Wv2);
  const float* bp = biasp + (seg == 0 ? 1 * 2048 + b * 512 : (seg == 1 ? 2 * 2048 : 3 * 2048));
  f16* Ob = (seg == 0 ? Ok : (seg == 1 ? Ov : Ov2)) + (size_t)b * 512 * 4096;
  __shared__ f16 As[2][4096];
  __shared__ f16 Bs[2][4096];
  const int t = threadIdx.x;
  const int lane = t & 63, wid = t >> 6;
  const int wm = (wid >> 1) * 64, wn = (wid & 1) * 64;
  const int lr = lane & 15, lg = lane >> 4;
  const int sr = lane >> 2, sc = lane & 3;
  auto STAGE = [&](int d, int kk){
    #pragma unroll
    for(int i = 0; i < 2; i++){
      int r0 = wid * 32 + i * 16;
      int rr = r0 + sr;
      int cs = (sc ^ ((rr >> 1) & 3)) << 3;
      glds16(Wb + (size_t)(o0 + rr) * 512 + kk + cs, As[d] + r0 * 32);
      glds16(Xb + (size_t)(s0 + rr) * 512 + kk + cs, Bs[d] + r0 * 32);
    }
  };
  f32x4 acc[4][4] = {};
  STAGE(0, 0);
  int db = 0;
  for(int tt = 0; tt < 16; tt++){
    if(tt < 15){
      STAGE(db ^ 1, (tt + 1) * 32);
      asm volatile("s_waitcnt vmcnt(4)" ::: "memory");
    } else {
      asm volatile("s_waitcnt vmcnt(0)" ::: "memory");
    }
    barrier_f();
    f16x8 av[4], bv[4];
    #pragma unroll
    for(int mi = 0; mi < 4; mi++){
      int row = wm + mi * 16 + lr;
      av[mi] = *(const f16x8*)(As[db] + row * 32 + ((lg ^ ((row >> 1) & 3)) << 3));
    }
    #pragma unroll
    for(int ni = 0; ni < 4; ni++){
      int row = wn + ni * 16 + lr;
      bv[ni] = *(const f16x8*)(Bs[db] + row * 32 + ((lg ^ ((row >> 1) & 3)) << 3));
    }
    #pragma unroll
    for(int mi = 0; mi < 4; mi++){
      #pragma unroll
      for(int ni = 0; ni < 4; ni++)
        acc[mi][ni] = mfma16(av[mi], bv[ni], acc[mi][ni]);
    }
    barrier_f();
    db ^= 1;
  }
  #pragma unroll
  for(int mi = 0; mi < 4; mi++){
    #pragma unroll
    for(int ni = 0; ni < 4; ni++){
      #pragma unroll
      for(int j = 0; j < 4; j++){
        int o = o0 + wm + mi * 16 + lg * 4 + j;
        int s = s0 + wn + ni * 16 + lr;
        Ob[(size_t)o * 4096 + s] = (f16)(acc[mi][ni][j] + bp[o]);
      }
    }
  }
}

// ============ 5. PA1 (f16 path) split-K MFMA ============
__global__ __launch_bounds__(256) void k_pa1(
    const f16* __restrict__ Qh, const f16* __restrict__ Kh, float* __restrict__ pa1p)
{
  const int slice = blockIdx.x & 7;
  const int bh = blockIdx.x >> 3;
  const size_t base = (size_t)bh * 64 * 4096;
  __shared__ f16 Ah[2][64][72], Bh[2][64][72];
  const int t = threadIdx.x;
  const int lane = t & 63, wid = t >> 6;
  const int wm = (wid >> 1) * 32, wn = (wid & 1) * 32;
  const int lr = lane & 15, lg = lane >> 4;
  f32x4 acc[2][2] = {};
  for(int chunk = 0; chunk < 4; chunk++){
    const int c0 = slice * 8 + chunk * 2;
    __syncthreads();
    #pragma unroll
    for(int cc = 0; cc < 2; cc++){
      size_t cbase = base + (size_t)(c0 + cc) * 4096;
      #pragma unroll
      for(int u = 0; u < 2; u++){
        int e = u * 256 + t;
        int x = e >> 3, yh = e & 7;
        size_t src = cbase + (size_t)((x >> 3) * 512 + (x & 7) * 8 + yh * 64);
        int dst = yh * 8;
        *(f16x8*)(&Ah[cc][x][dst]) = *(const f16x8*)(Qh + src);
        *(f16x8*)(&Bh[cc][x][dst]) = *(const f16x8*)(Kh + src);
      }
    }
    __syncthreads();
    #pragma unroll
    for(int cc = 0; cc < 2; cc++){
      #pragma unroll
      for(int kc = 0; kc < 2; kc++){
        f16x8 ah[2], bh[2];
        #pragma unroll
        for(int mi = 0; mi < 2; mi++)
          ah[mi] = *(const f16x8*)(&Ah[cc][wm + mi * 16 + lr][kc * 32 + lg * 8]);
        #pragma unroll
        for(int ni = 0; ni < 2; ni++)
          bh[ni] = *(const f16x8*)(&Bh[cc][wn + ni * 16 + lr][kc * 32 + lg * 8]);
        #pragma unroll
        for(int mi = 0; mi < 2; mi++){
          #pragma unroll
          for(int ni = 0; ni < 2; ni++)
            acc[mi][ni] = mfma16(ah[mi], bh[ni], acc[mi][ni]);
        }
      }
    }
  }
  float* outp = pa1p + ((size_t)bh * 8 + slice) * 4096;
  #pragma unroll
  for(int mi = 0; mi < 2; mi++){
    #pragma unroll
    for(int ni = 0; ni < 2; ni++){
      #pragma unroll
      for(int j = 0; j < 4; j++){
        int x = wm + mi * 16 + lg * 4 + j;
        int z = wn + ni * 16 + lr;
        outp[x * 64 + z] = acc[mi][ni][j];
      }
    }
  }
}

// ============ 5b. reduce partials + argmax + near-tie flag ============
__global__ __launch_bounds__(64) void k_pa1r(
    float* __restrict__ pa1p, int* __restrict__ idx, int* __restrict__ flags)
{
  const int bh = blockIdx.x;
  const int x = threadIdx.x;
  float* p = pa1p + (size_t)bh * 8 * 4096 + x * 64;
  float m1 = -3e38f, m2 = -3e38f; int i1 = 0;
  for(int z = 0; z < 64; z += 4){
    float4 v = *(const float4*)(p + z);
    #pragma unroll
    for(int sl = 1; sl < 8; sl++){
      float4 w = *(const float4*)(p + sl * 4096 + z);
      v.x += w.x; v.y += w.y; v.z += w.z; v.w += w.w;
    }
    *(float4*)(p + z) = v;
    float vv[4] = {v.x, v.y, v.z, v.w};
    #pragma unroll
    for(int k = 0; k < 4; k++){
      if(vv[k] > m1){ m2 = m1; m1 = vv[k]; i1 = z + k; }
      else if(vv[k] > m2){ m2 = vv[k]; }
    }
  }
  idx[bh * 64 + x] = i1;
  flags[bh * 64 + x] = (m2 >= m1 - 0.5f) ? 1 : 0;
}

// ============ 5c. exact refinement for near-tie argmax rows (pipelined gemm) ============
__global__ __launch_bounds__(256) void k_refine(
    const f16* __restrict__ Xqh, const f16* __restrict__ Xql,
    const f16* __restrict__ Xkh, const f16* __restrict__ Xkl,
    const f16* __restrict__ Wqh, const f16* __restrict__ Wql,
    const f16* __restrict__ Wkh, const f16* __restrict__ Wkl,
    const float* __restrict__ biasp, const float* __restrict__ pa1p,
    const int* __restrict__ flags, int* __restrict__ idx)
{
  const int bid = blockIdx.x;
  if(flags[bid] == 0) return;
  const int bh = bid >> 6, x = bid & 63;
  const int b = bh >> 3, hd = bh & 7;
  __shared__ __align__(16) f16 Ah[64][72], Al[64][72], Bh[64][72], Bl[64][72];
  __shared__ float q2s[64][65];
  __shared__ float red[4];
  __shared__ float vals[64];
  __shared__ int cand[64];
  const int t = threadIdx.x;
  const int lane = t & 63, wid = t >> 6;
  const int wm = (wid >> 1) * 32, wn = (wid & 1) * 32;
  const int lr = lane & 15, lg = lane >> 4;
  const int srw = t >> 2, soc = (t & 3) * 2;

  auto gemm = [&](const f16* Wh_, const f16* Wl_, const f16* Xh_, const f16* Xl_,
                  int blk, f32x4 (&acc)[2][2]){
    const size_t wrow = ((size_t)(b * 512 + hd * 64 + srw)) * 512 + soc * 8;
    const int s = (blk >> 3) * 512 + (blk & 7) * 8 + (srw >> 3) * 64 + (srw & 7);
    const size_t xrow = ((size_t)b * 4096 + s) * 512 + soc * 8;
    f16x8 r0, r1, r2, r3, r4, r5, r6, r7;
    #define RLOAD(ch, a0,a1,a2,a3,a4,a5,a6,a7) do{            \
      a0 = *(const f16x8*)(Wh_ + wrow + (ch) * 64);           \
      a1 = *(const f16x8*)(Wh_ + wrow + (ch) * 64 + 8);       \
      a2 = *(const f16x8*)(Wl_ + wrow + (ch) * 64);           \
      a3 = *(const f16x8*)(Wl_ + wrow + (ch) * 64 + 8);       \
      a4 = *(const f16x8*)(Xh_ + xrow + (ch) * 64);           \
      a5 = *(const f16x8*)(Xh_ + xrow + (ch) * 64 + 8);       \
      a6 = *(const f16x8*)(Xl_ + xrow + (ch) * 64);           \
      a7 = *(const f16x8*)(Xl_ + xrow + (ch) * 64 + 8);       \
    }while(0)
    RLOAD(0, r0,r1,r2,r3,r4,r5,r6,r7);
    #pragma unroll
    for(int ch = 0; ch < 8; ch++){
      __syncthreads();
      *(f16x8*)(&Ah[srw][soc * 8])     = r0;
      *(f16x8*)(&Ah[srw][soc * 8 + 8]) = r1;
      *(f16x8*)(&Al[srw][soc * 8])     = r2;
      *(f16x8*)(&Al[srw][soc * 8 + 8]) = r3;
      *(f16x8*)(&Bh[srw][soc * 8])     = r4;
      *(f16x8*)(&Bh[srw][soc * 8 + 8]) = r5;
      *(f16x8*)(&Bl[srw][soc * 8])     = r6;
      *(f16x8*)(&Bl[srw][soc * 8 + 8]) = r7;
      f16x8 n0, n1, n2, n3, n4, n5, n6, n7;
      if(ch < 7) RLOAD(ch + 1, n0,n1,n2,n3,n4,n5,n6,n7);
      __syncthreads();
      #pragma unroll
      for(int kc = 0; kc < 2; kc++){
        f16x8 ah[2], al[2], bh2[2], bl2[2];
        #pragma unroll
        for(int mi = 0; mi < 2; mi++){
          int row = wm + mi * 16 + lr;
          ah[mi] = *(const f16x8*)(&Ah[row][kc * 32 + lg * 8]);
          al[mi] = *(const f16x8*)(&Al[row][kc * 32 + lg * 8]);
        }
        #pragma unroll
        for(int ni = 0; ni < 2; ni++){
          int row = wn + ni * 16 + lr;
          bh2[ni] = *(const f16x8*)(&Bh[row][kc * 32 + lg * 8]);
          bl2[ni] = *(const f16x8*)(&Bl[row][kc * 32 + lg * 8]);
        }
        #pragma unroll
        for(int mi = 0; mi < 2; mi++){
          #pragma unroll
          for(int ni = 0; ni < 2; ni++){
            f32x4 a = acc[mi][ni];
            a = mfma16(ah[mi], bh2[ni], a);
            a = mfma16(ah[mi], bl2[ni], a);
            a = mfma16(al[mi], bh2[ni], a);
            acc[mi][ni] = a;
          }
        }
      }
      r0 = n0; r1 = n1; r2 = n2; r3 = n3;
      r4 = n4; r5 = n5; r6 = n6; r7 = n7;
    }
    #undef RLOAD
  };

  if(t < 64) vals[t] = pa1p[(size_t)bh * 8 * 4096 + x * 64 + t];
  __syncthreads();
  if(t == 0){
    float m1 = vals[0];
    for(int z = 1; z < 64; z++) m1 = fmaxf(m1, vals[z]);
    red[0] = m1;
  }
  __syncthreads();
  const float m1 = red[0];
  if(t < 64) cand[t] = (vals[t] >= m1 - 0.5f) ? 1 : 0;
  __syncthreads();

  {
    f32x4 qa[2][2] = {};
    gemm(Wqh, Wql, Xqh, Xql, x, qa);
    #pragma unroll
    for(int mi = 0; mi < 2; mi++){
      #pragma unroll
      for(int ni = 0; ni < 2; ni++){
        #pragma unroll
        for(int j = 0; j < 4; j++){
          int c = wm + mi * 16 + lg * 4 + j;
          int y = wn + ni * 16 + lr;
          q2s[c][y] = qa[mi][ni][j] + biasp[4 * 2048 + b * 512 + hd * 64 + c];
        }
      }
    }
  }
  __syncthreads();

  float bestv = -3e38f; int besti = 0;
  for(int z = 0; z < 64; z++){
    if(!cand[z]) continue;
    f32x4 ka[2][2] = {};
    gemm(Wkh, Wkl, Xkh, Xkl, z, ka);
    float part = 0.f;
    #pragma unroll
    for(int mi = 0; mi < 2; mi++){
      #pragma unroll
      for(int ni = 0; ni < 2; ni++){
        #pragma unroll
        for(int j = 0; j < 4; j++){
          int c = wm + mi * 16 + lg * 4 + j;
          int y = wn + ni * 16 + lr;
          part += (ka[mi][ni][j] + biasp[5 * 2048 + b * 512 + hd * 64 + c]) * q2s[c][y];
        }
      }
    }
    #pragma unroll
    for(int off = 32; off > 0; off >>= 1) part += __shfl_xor(part, off);
    __syncthreads();
    if(lane == 0) red[wid] = part;
    __syncthreads();
    float pv = red[0] + red[1] + red[2] + red[3];
    if(pv > bestv){ bestv = pv; besti = z; }
  }
  if(t == 0) idx[bid] = besti;
}

// ============ 6. DA aggregation — XCD-grouped ============
__global__ __launch_bounds__(256) void k_da1(
    const f16* __restrict__ K, const f16* __restrict__ V,
    const float* __restrict__ alpha_p, const float* __restrict__ beta_p,
    float* __restrict__ kagg, float* __restrict__ vagg)
{
  const int hw = blockIdx.x;
  const int xcd = hw & 7, i = hw >> 3;
  const int g = xcd * 32 + (i >> 3);
  const int bh = g >> 3;
  const int x  = (g & 7) * 8 + (i & 7);
  const f16* Kb = K + (size_t)bh * 64 * 4096;
  const f16* Vb = V + (size_t)bh * 64 * 4096;
  __shared__ float kl[64][65];
  __shared__ float vl[64][65];
  __shared__ float kc[64], vc[64], simv[64];
  const int t = threadIdx.x;
  const int c = t >> 2, yp = t & 3;
  const int xb = (x >> 3) * 512 + (x & 7) * 8;
  #pragma unroll
  for(int u = 0; u < 2; u++){
    int yh = yp * 2 + u;
    f16x8 k8 = *(const f16x8*)(Kb + (size_t)c * 4096 + xb + yh * 64);
    f16x8 v8 = *(const f16x8*)(Vb + (size_t)c * 4096 + xb + yh * 64);
    #pragma unroll
    for(int j = 0; j < 8; j++){
      kl[c][yh * 8 + j] = (float)k8[j];
      vl[c][yh * 8 + j] = (float)v8[j];
    }
  }
  __syncthreads();
  float sk = 0.f, sv = 0.f;
  for(int yy = yp * 16; yy < yp * 16 + 16; yy++){ sk += kl[c][yy]; sv += vl[c][yy]; }
  sk += __shfl_xor(sk, 1); sk += __shfl_xor(sk, 2);
  sv += __shfl_xor(sv, 1); sv += __shfl_xor(sv, 2);
  if(yp == 0){ kc[c] = sk * (1.f / 64.f); vc[c] = sv * (1.f / 64.f); }
  __syncthreads();
  const int y = t >> 2, cp = t & 3;
  float d = 0.f;
  for(int cc = cp * 16; cc < cp * 16 + 16; cc++) d += kc[cc] * kl[cc][y];
  d += __shfl_xor(d, 1); d += __shfl_xor(d, 2);
  if(cp == 0) simv[y] = 1.f / (1.f + expf(-(beta_p[0] + alpha_p[0] * d)));
  __syncthreads();
  float ak = 0.f, av = 0.f;
  for(int yy = yp * 16; yy < yp * 16 + 16; yy++){
    float sm = simv[yy];
    ak += sm * kl[c][yy]; av += sm * vl[c][yy];
  }
  ak += __shfl_xor(ak, 1); ak += __shfl_xor(ak, 2);
  av += __shfl_xor(av, 1); av += __shfl_xor(av, 2);
  if(yp == 0){
    size_t o = ((size_t)bh * 64 + x) * 64 + c;
    kagg[o] = (ak + kc[c]) * (1.f / 65.f);
    vagg[o] = (av + vc[c]) * (1.f / 65.f);
  }
}

// ============ 7. DA attention MFMA; output TRANSPOSED [s][c] ============
__global__ __launch_bounds__(256) void k_da2(
    const f16* __restrict__ Q, const float* __restrict__ kagg,
    const float* __restrict__ vagg, f16* __restrict__ OutT)
{
  const int bh = blockIdx.x >> 4;
  const int s0 = (blockIdx.x & 15) << 8;
  const int b_ = bh >> 3, hd = bh & 7;
  const f16* Qb = Q + (size_t)bh * 64 * 4096;
  f16* Ot = OutT + (size_t)b_ * 4096 * 512 + hd * 64;

  __shared__ __align__(16) f16 Qt[256][72];
  __shared__ __align__(16) f16 Kt[64][72];
  __shared__ __align__(16) f16 Vt[64][72];
  const int t = threadIdx.x;
  const int lane = t & 63, w = t >> 6;
  const int lr = lane & 15, lg = lane >> 4;

  {
    const int so = t & 31;
    #pragma unroll
    for(int pass = 0; pass < 8; pass++){
      int c = (t >> 5) + pass * 8;
      f16x8 q8 = *(const f16x8*)(Qb + (size_t)c * 4096 + s0 + so * 8);
      #pragma unroll
      for(int j = 0; j < 8; j++){
        int s = so * 8 + j;
        int col = (((c >> 3) ^ (s & 7)) << 3) | (c & 7);
        Qt[s][col] = q8[j];
      }
    }
  }
  {
    const int z = t >> 2, c0 = (t & 3) * 16;
    #pragma unroll
    for(int u = 0; u < 4; u++){
      float4 v = *(const float4*)(kagg + (size_t)bh * 4096 + z * 64 + c0 + u * 4);
      float vv[4] = {v.x, v.y, v.z, v.w};
      #pragma unroll
      for(int j = 0; j < 4; j++){
        int c = c0 + u * 4 + j;
        int col = (((c >> 3) ^ (z & 7)) << 3) | (c & 7);
        Kt[z][col] = (f16)vv[j];
      }
    }
    #pragma unroll
    for(int u = 0; u < 4; u++){
      float4 v = *(const float4*)(vagg + (size_t)bh * 4096 + z * 64 + c0 + u * 4);
      float vv[4] = {v.x, v.y, v.z, v.w};
      #pragma unroll
      for(int j = 0; j < 4; j++){
        int c = c0 + u * 4 + j;
        int col = (((z >> 3) ^ (c & 7)) << 3) | (z & 7);
        Vt[c][col] = (f16)vv[j];
      }
    }
  }
  __syncthreads();

  f32x4 acc[4][4] = {};
  #pragma unroll
  for(int kc = 0; kc < 2; kc++){
    f16x8 af[4], bf[4];
    #pragma unroll
    for(int mi = 0; mi < 4; mi++){
      int row = w * 64 + mi * 16 + lr;
      af[mi] = *(const f16x8*)(&Qt[row][(((kc * 4 + lg) ^ (row & 7)) << 3)]);
    }
    #pragma unroll
    for(int ni = 0; ni < 4; ni++){
      int row = ni * 16 + lr;
      bf[ni] = *(const f16x8*)(&Kt[row][(((kc * 4 + lg) ^ (row & 7)) << 3)]);
    }
    #pragma unroll
    for(int mi = 0; mi < 4; mi++){
      #pragma unroll
      for(int ni = 0; ni < 4; ni++)
        acc[mi][ni] = mfma16(af[mi], bf[ni], acc[mi][ni]);
    }
  }

  #pragma unroll
  for(int mi = 0; mi < 4; mi++){
    #pragma unroll
    for(int j = 0; j < 4; j++){
      float v0 = acc[mi][0][j], v1 = acc[mi][1][j], v2 = acc[mi][2][j], v3 = acc[mi][3][j];
      float m = fmaxf(fmaxf(v0, v1), fmaxf(v2, v3));
      m = fmaxf(m, __shfl_xor(m, 1)); m = fmaxf(m, __shfl_xor(m, 2));
      m = fmaxf(m, __shfl_xor(m, 4)); m = fmaxf(m, __shfl_xor(m, 8));
      float e0 = expf(v0 - m), e1 = expf(v1 - m), e2 = expf(v2 - m), e3 = expf(v3 - m);
      float sm = e0 + e1 + e2 + e3;
      sm += __shfl_xor(sm, 1); sm += __shfl_xor(sm, 2);
      sm += __shfl_xor(sm, 4); sm += __shfl_xor(sm, 8);
      float inv = 1.f / sm;
      float ev[4] = {e0, e1, e2, e3};
      int row = w * 64 + mi * 16 + lg * 4 + j;
      #pragma unroll
      for(int ni = 0; ni < 4; ni++){
        int z = lr + 16 * ni;
        int col = (((z >> 3) ^ (row & 7)) << 3) | (z & 7);
        Qt[row][col] = (f16)(ev[ni] * inv);
      }
    }
  }

  f32x4 acc2[4][4] = {};
  #pragma unroll
  for(int kc = 0; kc < 2; kc++){
    f16x8 af[4], bf[4];
    #pragma unroll
    for(int mi = 0; mi < 4; mi++){
      int row = w * 64 + mi * 16 + lr;
      af[mi] = *(const f16x8*)(&Qt[row][(((kc * 4 + lg) ^ (row & 7)) << 3)]);
    }
    #pragma unroll
    for(int ni = 0; ni < 4; ni++){
      int row = ni * 16 + lr;
      bf[ni] = *(const f16x8*)(&Vt[row][(((kc * 4 + lg) ^ (row & 7)) << 3)]);
    }
    #pragma unroll
    for(int mi = 0; mi < 4; mi++){
      #pragma unroll
      for(int ni = 0; ni < 4; ni++)
        acc2[mi][ni] = mfma16(af[mi], bf[ni], acc2[mi][ni]);
    }
  }

  #pragma unroll
  for(int mi = 0; mi < 4; mi++){
    #pragma unroll
    for(int j = 0; j < 4; j++){
      size_t srow = (size_t)(s0 + w * 64 + mi * 16 + lg * 4 + j) * 512;
      #pragma unroll
      for(int ni = 0; ni < 4; ni++)
        Ot[srow + ni * 16 + lr] = (f16)acc2[mi][ni][j];
    }
  }
}

// ============ 9. PA intra-block attention; output TRANSPOSED [s][c] ============
__global__ __launch_bounds__(256) void k_pa2(
    const f16* __restrict__ Qh, const f16* __restrict__ Kh,
    const f16* __restrict__ V2, const int* __restrict__ idx, f16* __restrict__ OutT)
{
  const int hw = blockIdx.x;
  const int bh = (hw & 7) * 4 + ((hw >> 3) >> 6);
  const int x  = (hw >> 3) & 63;
  const int b_ = bh >> 3, hd = bh & 7;
  const size_t base = (size_t)bh * 64 * 4096;
  f16* Ot = OutT + (size_t)b_ * 4096 * 512 + hd * 64;

  __shared__ __align__(16) char Ubuf[18432];
  __shared__ f16 Vn[64][72];
  __shared__ f16 Ps[64][72];
  f16   (*Qt)[72] = (f16(*)[72])Ubuf;
  f16   (*Kt)[72] = (f16(*)[72])(Ubuf + 9216);
  float (*Lf)[66] = (float(*)[66])Ubuf;
  float (*Os)[67] = (float(*)[67])Ubuf;

  const int t = threadIdx.x;
  const int lane = t & 63, wid = t >> 6;
  const int wm = (wid >> 1) * 32, wn = (wid & 1) * 32;
  const int lr = lane & 15, lg = lane >> 4;

  const int xk = idx[bh * 64 + x];
  const int xb = (x >> 3) * 512 + (x & 7) * 8;
  const int kb = (xk >> 3) * 512 + (xk & 7) * 8;

  {
    const int c = t >> 2, q4 = t & 3;
    #pragma unroll
    for(int u = 0; u < 2; u++){
      int yh = q4 * 2 + u;
      f16x8 q8 = *(const f16x8*)(Qh + base + (size_t)c * 4096 + xb + yh * 64);
      f16x8 k8 = *(const f16x8*)(Kh + base + (size_t)c * 4096 + kb + yh * 64);
      f16x8 v8 = *(const f16x8*)(V2 + base + (size_t)c * 4096 + kb + yh * 64);
      int col = ((((c >> 3) ^ yh) & 7) << 3) + (c & 7);
      #pragma unroll
      for(int j = 0; j < 8; j++){
        Qt[yh * 8 + j][col] = q8[j];
        Kt[yh * 8 + j][col] = k8[j];
      }
      *(f16x8*)(&Vn[c][yh * 8]) = v8;
    }
  }
  __syncthreads();

  f32x4 acc[2][2] = {};
  #pragma unroll
  for(int kc = 0; kc < 2; kc++){
    f16x8 af[2], bf[2];
    #pragma unroll
    for(int mi = 0; mi < 2; mi++){
      int row = wm + mi * 16 + lr;
      af[mi] = *(const f16x8*)(&Qt[row][((((kc * 4 + lg) ^ (row >> 3)) & 7) << 3)]);
    }
    #pragma unroll
    for(int ni = 0; ni < 2; ni++){
      int row = wn + ni * 16 + lr;
      bf[ni] = *(const f16x8*)(&Kt[row][((((kc * 4 + lg) ^ (row >> 3)) & 7) << 3)]);
    }
    #pragma unroll
    for(int mi = 0; mi < 2; mi++){
      #pragma unroll
      for(int ni = 0; ni < 2; ni++)
        acc[mi][ni] = mfma16(af[mi], bf[ni], acc[mi][ni]);
    }
  }
  __syncthreads();
  #pragma unroll
  for(int mi = 0; mi < 2; mi++){
    #pragma unroll
    for(int ni = 0; ni < 2; ni++){
      #pragma unroll
      for(int j = 0; j < 4; j++)
        Lf[wm + mi * 16 + lg * 4 + j][wn + ni * 16 + lr] = acc[mi][ni][j];
    }
  }
  __syncthreads();

  {
    const int y = t >> 2, zp = t & 3;
    float l[16];
    #pragma unroll
    for(int i = 0; i < 16; i++) l[i] = Lf[y][zp * 16 + i];
    float m = l[0];
    #pragma unroll
    for(int i = 1; i < 16; i++) m = fmaxf(m, l[i]);
    m = fmaxf(m, __shfl_xor(m, 1)); m = fmaxf(m, __shfl_xor(m, 2));
    float sum = 0.f;
    #pragma unroll
    for(int i = 0; i < 16; i++){ l[i] = expf(l[i] - m); sum += l[i]; }
    sum += __shfl_xor(sum, 1); sum += __shfl_xor(sum, 2);
    float inv = 1.f / sum;
    f16x8 p0, p1;
    #pragma unroll
    for(int i = 0; i < 8; i++){ p0[i] = (f16)(l[i] * inv); p1[i] = (f16)(l[8 + i] * inv); }
    *(f16x8*)(&Ps[y][zp * 16]) = p0;
    *(f16x8*)(&Ps[y][zp * 16 + 8]) = p1;
  }
  __syncthreads();

  f32x4 acc2[2][2] = {};
  #pragma unroll
  for(int kc = 0; kc < 2; kc++){
    f16x8 af[2], bf[2];
    #pragma unroll
    for(int mi = 0; mi < 2; mi++)
      af[mi] = *(const f16x8*)(&Ps[wm + mi * 16 + lr][kc * 32 + lg * 8]);
    #pragma unroll
    for(int ni = 0; ni < 2; ni++)
      bf[ni] = *(const f16x8*)(&Vn[wn + ni * 16 + lr][kc * 32 + lg * 8]);
    #pragma unroll
    for(int mi = 0; mi < 2; mi++){
      #pragma unroll
      for(int ni = 0; ni < 2; ni++)
        acc2[mi][ni] = mfma16(af[mi], bf[ni], acc2[mi][ni]);
    }
  }
  #pragma unroll
  for(int mi = 0; mi < 2; mi++){
    #pragma unroll
    for(int ni = 0; ni < 2; ni++){
      #pragma unroll
      for(int j = 0; j < 4; j++)
        Os[wn + ni * 16 + lr][wm + mi * 16 + lg * 4 + j] = acc2[mi][ni][j];
    }
  }
  __syncthreads();

  {
    const int y = t >> 2, cq = (t & 3) * 16;
    size_t srow = (size_t)(xb + (y >> 3) * 64 + (y & 7)) * 512;
    f16x8 w0, w1;
    #pragma unroll
    for(int i = 0; i < 8; i++){ w0[i] = (f16)Os[cq + i][y]; w1[i] = (f16)Os[cq + 8 + i][y]; }
    *(f16x8*)(Ot + srow + cq) = w0;
    *(f16x8*)(Ot + srow + cq + 8) = w1;
  }
}

// ============ 10. Final: 128x128 tile, 2 passes ============
__global__ __launch_bounds__(256) void k_finalT(
    const f16* __restrict__ X1t, const f16* __restrict__ X2t,
    const f16* __restrict__ W1p, const f16* __restrict__ W2p,
    const float* __restrict__ B1, const float* __restrict__ B2,
    const float* __restrict__ content, float* __restrict__ out)
{
  const int b = blockIdx.z;
  const int o0 = blockIdx.y * 128;
  const int s0 = blockIdx.x * 128;
  __shared__ f16 As[2][4096];
  __shared__ f16 Bs[2][4096];
  const int t = threadIdx.x;
  const int lane = t & 63, wid = t >> 6;
  const int wm = (wid >> 1) * 64, wn = (wid & 1) * 64;
  const int lr = lane & 15, lg = lane >> 4;
  const int sr = lane >> 2, sc = lane & 3;
  const f16* Xp[2] = {X1t + (size_t)b * 4096 * 512, X2t + (size_t)b * 4096 * 512};
  const f16* Wq[2] = {W1p, W2p};
  auto STAGE = [&](int d, int tt){
    const f16* Xb = Xp[tt >> 4];
    const f16* Wb = Wq[tt >> 4];
    int kk = (tt & 15) * 32;
    #pragma unroll
    for(int i = 0; i < 2; i++){
      int r0 = wid * 32 + i * 16;
      int rr = r0 + sr;
      int cs = (sc ^ ((rr >> 1) & 3)) << 3;
      glds16(Wb + (size_t)(o0 + rr) * 512 + kk + cs, As[d] + r0 * 32);
      glds16(Xb + (size_t)(s0 + rr) * 512 + kk + cs, Bs[d] + r0 * 32);
    }
  };
  f32x4 acc[4][4] = {};
  STAGE(0, 0);
  int db = 0;
  for(int tt = 0; tt < 32; tt++){
    if(tt < 31){
      STAGE(db ^ 1, tt + 1);
      asm volatile("s_waitcnt vmcnt(4)" ::: "memory");
    } else {
      asm volatile("s_waitcnt vmcnt(0)" ::: "memory");
    }
    barrier_f();
    f16x8 av[4], bv[4];
    #pragma unroll
    for(int mi = 0; mi < 4; mi++){
      int row = wm + mi * 16 + lr;
      av[mi] = *(const f16x8*)(As[db] + row * 32 + ((lg ^ ((row >> 1) & 3)) << 3));
    }
    #pragma unroll
    for(int ni = 0; ni < 4; ni++){
      int row = wn + ni * 16 + lr;
      bv[ni] = *(const f16x8*)(Bs[db] + row * 32 + ((lg ^ ((row >> 1) & 3)) << 3));
    }
    #pragma unroll
    for(int mi = 0; mi < 4; mi++){
      #pragma unroll
      for(int ni = 0; ni < 4; ni++)
        acc[mi][ni] = mfma16(av[mi], bv[ni], acc[mi][ni]);
    }
    barrier_f();
    db ^= 1;
  }
  #pragma unroll
  for(int mi = 0; mi < 4; mi++){
    #pragma unroll
    for(int ni = 0; ni < 4; ni++){
      #pragma unroll
      for(int j = 0; j < 4; j++){
        int o = o0 + wm + mi * 16 + lg * 4 + j;
        int s = s0 + wn + ni * 16 + lr;
        size_t gi = ((size_t)b * 512 + o) * 4096 + s;
        out[gi] = acc[mi][ni][j] + B1[o] + B2[o] + content[gi];
      }
    }
  }
}

extern "C" void kernel_launch(void* const* d_in, const int* in_sizes, int n_in,
                              void* d_out, int out_size, void* d_ws, size_t ws_size,
                              hipStream_t stream) {
  (void)in_sizes; (void)n_in; (void)out_size; (void)ws_size;
  const float* content = (const float*)d_in[0];
  const float* style   = (const float*)d_in[1];
  const float* q_w  = (const float*)d_in[2];  const float* q_b  = (const float*)d_in[3];
  const float* k_w  = (const float*)d_in[4];  const float* k_b  = (const float*)d_in[5];
  const float* v_w  = (const float*)d_in[6];  const float* v_b  = (const float*)d_in[7];
  const float* q2_w = (const float*)d_in[8];  const float* q2_b = (const float*)d_in[9];
  const float* k2_w = (const float*)d_in[10]; const float* k2_b = (const float*)d_in[11];
  const float* v2_w = (const float*)d_in[12]; const float* v2_b = (const float*)d_in[13];
  const float* f1_w = (const float*)d_in[14]; const float* f1_b = (const float*)d_in[15];
  const float* f2_w = (const float*)d_in[16]; const float* f2_b = (const float*)d_in[17];
  const float* sim_alpha = (const float*)d_in[18];
  const float* sim_beta  = (const float*)d_in[19];

  char* ws = (char*)d_ws;
  #define SLOT(i) (ws + (size_t)(i) * 16777216)
  f16* cth = (f16*)SLOT(0);
  f16* ctl = (f16*)SLOT(1);
  f16* sth = (f16*)SLOT(2);
  f16* stl = (f16*)SLOT(3);
  f16* wbase = (f16*)SLOT(4);
  f16* qw   = wbase;
  f16* kw   = wbase + 1 * 1048576;
  f16* q2wh = wbase + 2 * 1048576;
  f16* q2wl = wbase + 3 * 1048576;
  f16* k2wh = wbase + 4 * 1048576;
  f16* k2wl = wbase + 5 * 1048576;
  f16* vw   = wbase + 6 * 1048576;
  f16* v2w  = vw + 262144;
  f16* f1w  = vw + 524288;
  f16* f2w  = vw + 786432;
  f16*   q2h   = (f16*)SLOT(5);
  f16*   k2h   = (f16*)SLOT(6);
  float* pa1p  = (float*)SLOT(7);
  int*   flags = (int*)(ws + 7 * 16777216 + 8388608);
  f16*   qbuf  = (f16*)SLOT(3);      // stl dead after refine
  f16*   kbuf  = (f16*)SLOT(0);      // cth dead after convT(q)
  f16*   vbuf  = (f16*)SLOT(1);      // ctl dead after refine
  f16*   v2buf = (f16*)SLOT(7);      // pa1p/flags dead after refine
  f16*   da_t  = (f16*)SLOT(2);      // sth dead after conv3out
  f16*   pa_t  = (f16*)SLOT(3);      // qbuf dead after da2
  float* stats = (float*)(ws + 134217728);
  float* biasp = (float*)(ws + 134217728 + 32768);
  float* kagg  = (float*)(ws + 134217728 + 32768);
  float* vagg  = (float*)(ws + 134217728 + 557056);
  int*   idxb  = (int*)(ws + 134217728 + 1081344);

  dim3 gconv(32, 4, 4);

  // zero raw-moment accumulators (S/SS), then prep_x accumulates them
  hipMemsetAsync(stats, 0, 32768, stream);

  k_prep_x<<<dim3(32,4,2), 256, 0, stream>>>(content, style, cth, ctl, sth, stl, stats);

  k_prep_w_all<<<320, 256, 0, stream>>>(
      q_w, q_b, k_w, k_b, q2_w, q2_b, k2_w, k2_b,
      v_w, v_b, v2_w, v2_b, f1_w, f2_w, stats,
      qw, kw, q2wh, q2wl, k2wh, k2wl, vw, v2w, f1w, f2w, biasp);

  // q2/k2 projections in plain f16 (argmax near-ties repaired by k_refine)
  k_convT<<<gconv, 256, 0, stream>>>(cth, q2wh, biasp + 4 * 2048, 1, q2h);
  k_convT<<<gconv, 256, 0, stream>>>(sth, k2wh, biasp + 5 * 2048, 1, k2h);
  k_pa1<<<256, 256, 0, stream>>>(q2h, k2h, pa1p);
  k_pa1r<<<32, 64, 0, stream>>>(pa1p, idxb, flags);
  k_refine<<<2048, 256, 0, stream>>>(cth, ctl, sth, stl,
                                     q2wh, q2wl, k2wh, k2wl,
                                     biasp, pa1p, flags, idxb);

  k_convT<<<gconv, 256, 0, stream>>>(cth, qw, biasp + 0 * 2048, 1, qbuf);
  k_conv3out<<<dim3(32,12,4), 256, 0, stream>>>(sth, kw, vw, v2w, biasp,
                                                kbuf, vbuf, v2buf);

  k_da1<<<2048, 256, 0, stream>>>(kbuf, vbuf, sim_alpha, sim_beta, kagg, vagg);
  k_da2<<<512, 256, 0, stream>>>(qbuf, kagg, vagg, da_t);
  k_pa2<<<2048, 256, 0, stream>>>(q2h, k2h, v2buf, idxb, pa_t);

  k_finalT<<<gconv, 256, 0, stream>>>(da_t, pa_t, f1w, f2w, f1_b, f2_b,
                                      content, (float*)d_out);
}

// Round 15
// 291.453 us; speedup vs baseline: 1.1590x; 1.0451x over previous
//
#include <hip/hip_runtime.h>

typedef unsigned short u16;
typedef unsigned int   u32;
typedef _Float16       f16;

typedef f16   f16x8 __attribute__((ext_vector_type(8)));
typedef f16   f16x4 __attribute__((ext_vector_type(4)));
typedef float f32x4 __attribute__((ext_vector_type(4)));

__device__ __forceinline__ f32x4 mfma16(f16x8 a, f16x8 b, f32x4 c){
  return __builtin_amdgcn_mfma_f32_16x16x32_f16(a, b, c, 0, 0, 0);
}

// async global->LDS, 16B per lane; LDS dest = wave-uniform base + lane*16 (linear)
__device__ __forceinline__ void glds16(const f16* g, f16* l){
  __builtin_amdgcn_global_load_lds(
      (const __attribute__((address_space(1))) void*)g,
      (__attribute__((address_space(3))) void*)l, 16, 0, 0);
}

__device__ __forceinline__ void barrier_f(){
  __builtin_amdgcn_s_barrier();
  asm volatile("" ::: "memory");
}

// ============ 2. ALL weight preps: mean/rstd computed from raw S/SS sums ============
__global__ __launch_bounds__(256) void k_prep_w_all(
    const float* __restrict__ qW,  const float* __restrict__ qB,
    const float* __restrict__ kW,  const float* __restrict__ kB,
    const float* __restrict__ q2W, const float* __restrict__ q2B,
    const float* __restrict__ k2W, const float* __restrict__ k2B,
    const float* __restrict__ vW,  const float* __restrict__ vB,
    const float* __restrict__ v2W, const float* __restrict__ v2B,
    const float* __restrict__ f1W, const float* __restrict__ f2W,
    const float* __restrict__ stats,
    f16* __restrict__ qw, f16* __restrict__ kw,
    f16* __restrict__ q2wh, f16* __restrict__ q2wl,
    f16* __restrict__ k2wh, f16* __restrict__ k2wl,
    f16* __restrict__ vw, f16* __restrict__ v2w,
    f16* __restrict__ f1w, f16* __restrict__ f2w,
    float* __restrict__ biasp)
{
  const int t = threadIdx.x;
  int rid = blockIdx.x * 32 + (t >> 3);
  const float *W; const float *B = nullptr;
  int side = -1, b = 0, o;
  f16 *oh; f16 *ol = nullptr; float* bs = nullptr;
  if(rid < 2048){
    b = rid >> 9; o = rid & 511;
    W = qW; B = qB; side = 0;
    oh = qw + (size_t)(b * 512 + o) * 512;
    bs = biasp + 0 * 2048 + b * 512 + o;
  } else if(rid < 4096){
    rid -= 2048; b = rid >> 9; o = rid & 511;
    W = kW; B = kB; side = 1;
    oh = kw + (size_t)(b * 512 + o) * 512;
    bs = biasp + 1 * 2048 + b * 512 + o;
  } else if(rid < 6144){
    rid -= 4096; b = rid >> 9; o = rid & 511;
    W = q2W; B = q2B; side = 0;
    oh = q2wh + (size_t)(b * 512 + o) * 512;
    ol = q2wl + (size_t)(b * 512 + o) * 512;
    bs = biasp + 4 * 2048 + b * 512 + o;
  } else if(rid < 8192){
    rid -= 6144; b = rid >> 9; o = rid & 511;
    W = k2W; B = k2B; side = 1;
    oh = k2wh + (size_t)(b * 512 + o) * 512;
    ol = k2wl + (size_t)(b * 512 + o) * 512;
    bs = biasp + 5 * 2048 + b * 512 + o;
  } else if(rid < 8704){
    o = rid - 8192; W = vW; B = vB;
    oh = vw + (size_t)o * 512;
    bs = biasp + 2 * 2048 + o;
  } else if(rid < 9216){
    o = rid - 8704; W = v2W; B = v2B;
    oh = v2w + (size_t)o * 512;
    bs = biasp + 3 * 2048 + o;
  } else if(rid < 9728){
    o = rid - 9216; W = f1W;
    oh = f1w + (size_t)o * 512;
  } else {
    o = rid - 9728; W = f2W;
    oh = f2w + (size_t)o * 512;
  }
  const float* Sv  = (side >= 0) ? stats + side * 4096 + b * 512 : nullptr;
  const float* SSv = Sv ? Sv + 2048 : nullptr;
  const int c0 = (t & 7) * 64;
  float dot = 0.f;
  #pragma unroll
  for(int i = 0; i < 64; i += 8){
    int c = c0 + i;
    float w[8];
    *(float4*)(w)     = *(const float4*)(W + (size_t)o * 512 + c);
    *(float4*)(w + 4) = *(const float4*)(W + (size_t)o * 512 + c + 4);
    f16x8 h8, l8;
    #pragma unroll
    for(int j = 0; j < 8; j++){
      float wp = w[j];
      if(side >= 0){
        float S = Sv[c + j], SS = SSv[c + j];
        float mean = S * (1.f / 4096.f);
        float r = rsqrtf((SS - S * mean) * (1.f / 4095.f) + 1e-5f);
        dot += wp * mean * r;
        wp *= r;
      }
      f16 h = (f16)wp;
      h8[j] = h; l8[j] = (f16)(wp - (float)h);
    }
    *(f16x8*)(oh + c) = h8;
    if(ol) *(f16x8*)(ol + c) = l8;
  }
  if(bs){
    dot += __shfl_xor(dot, 1); dot += __shfl_xor(dot, 2); dot += __shfl_xor(dot, 4);
    if((t & 7) == 0) *bs = B[o] - dot;
  }
}

// ============ 3. X prep: transpose + hi/lo split + fused MVN stats; c-chunked grid ============
__global__ __launch_bounds__(256) void k_prep_x(
    const float* __restrict__ content, const float* __restrict__ style,
    f16* __restrict__ cth, f16* __restrict__ ctl,
    f16* __restrict__ sth, f16* __restrict__ stl,
    float* __restrict__ stats)
{
  const int side = blockIdx.z;
  const int b = blockIdx.y >> 2;
  const int ch0 = (blockIdx.y & 3) * 128;   // 128-channel chunk
  const int s0 = blockIdx.x * 128;
  const float* Xb = (side ? style : content) + (size_t)b * 512 * 4096;
  f16* Oh = (side ? sth : cth) + (size_t)b * 4096 * 512;
  f16* Ol = (side ? stl : ctl) + (size_t)b * 4096 * 512;
  float* Sg = stats + side * 4096 + b * 512;
  __shared__ float Xs[32][132];
  const int t = threadIdx.x;
  const int s = t >> 1, half = t & 1;
  for(int cc = ch0; cc < ch0 + 128; cc += 32){
    __syncthreads();
    #pragma unroll
    for(int u = 0; u < 4; u++){
      int q = t + u * 256;
      int row = q >> 5, f4 = q & 31;
      float4 v = *(const float4*)(Xb + (size_t)(cc + row) * 4096 + s0 + f4 * 4);
      *(float4*)(&Xs[row][f4 * 4]) = v;
    }
    __syncthreads();
    f16x8 h0, h1, l0, l1;
    #pragma unroll
    for(int i = 0; i < 8; i++){
      float x = Xs[half * 16 + i][s];
      f16 h = (f16)x; h0[i] = h; l0[i] = (f16)(x - (float)h);
    }
    #pragma unroll
    for(int i = 0; i < 8; i++){
      float x = Xs[half * 16 + 8 + i][s];
      f16 h = (f16)x; h1[i] = h; l1[i] = (f16)(x - (float)h);
    }
    size_t o = (size_t)(s0 + s) * 512 + cc + half * 16;
    *(f16x8*)(Oh + o) = h0; *(f16x8*)(Oh + o + 8) = h1;
    *(f16x8*)(Ol + o) = l0; *(f16x8*)(Ol + o + 8) = l1;
    // fused MVN partial sums: 32 c-rows x 128 s from Xs
    {
      const int cl = t >> 3, part = t & 7;
      float s1 = 0.f, s2 = 0.f;
      #pragma unroll
      for(int i = 0; i < 16; i++){
        float xv = Xs[cl][part * 16 + i];
        s1 += xv; s2 += xv * xv;
      }
      s1 += __shfl_xor(s1, 1); s1 += __shfl_xor(s1, 2); s1 += __shfl_xor(s1, 4);
      s2 += __shfl_xor(s2, 1); s2 += __shfl_xor(s2, 2); s2 += __shfl_xor(s2, 4);
      if(part == 0){
        atomicAdd(Sg + cc + cl, s1);
        atomicAdd(Sg + 2048 + cc + cl, s2);
      }
    }
  }
}

// ============ 4. conv1x1 GEMM, 128x128 tile, dbuf glds + counted vmcnt ============
__global__ __launch_bounds__(256) void k_convT(
    const f16* __restrict__ Xt, const f16* __restrict__ Wp,
    const float* __restrict__ bias, int bw, f16* __restrict__ Out)
{
  const int b = blockIdx.z;
  const int o0 = blockIdx.y * 128;
  const int s0 = blockIdx.x * 128;
  const f16* Xb = Xt + (size_t)b * 4096 * 512;
  const f16* Wb = Wp + (bw ? (size_t)b * 262144 : 0);
  const float* bp = bias + (bw ? b * 512 : 0);
  f16* Ob = Out + (size_t)b * 512 * 4096;
  __shared__ f16 As[2][4096];
  __shared__ f16 Bs[2][4096];
  const int t = threadIdx.x;
  const int lane = t & 63, wid = t >> 6;
  const int wm = (wid >> 1) * 64, wn = (wid & 1) * 64;
  const int lr = lane & 15, lg = lane >> 4;
  const int sr = lane >> 2, sc = lane & 3;
  auto STAGE = [&](int d, int kk){
    #pragma unroll
    for(int i = 0; i < 2; i++){
      int r0 = wid * 32 + i * 16;
      int rr = r0 + sr;
      int cs = (sc ^ ((rr >> 1) & 3)) << 3;
      glds16(Wb + (size_t)(o0 + rr) * 512 + kk + cs, As[d] + r0 * 32);
      glds16(Xb + (size_t)(s0 + rr) * 512 + kk + cs, Bs[d] + r0 * 32);
    }
  };
  f32x4 acc[4][4] = {};
  STAGE(0, 0);
  int db = 0;
  for(int tt = 0; tt < 16; tt++){
    if(tt < 15){
      STAGE(db ^ 1, (tt + 1) * 32);
      asm volatile("s_waitcnt vmcnt(4)" ::: "memory");
    } else {
      asm volatile("s_waitcnt vmcnt(0)" ::: "memory");
    }
    barrier_f();
    f16x8 av[4], bv[4];
    #pragma unroll
    for(int mi = 0; mi < 4; mi++){
      int row = wm + mi * 16 + lr;
      av[mi] = *(const f16x8*)(As[db] + row * 32 + ((lg ^ ((row >> 1) & 3)) << 3));
    }
    #pragma unroll
    for(int ni = 0; ni < 4; ni++){
      int row = wn + ni * 16 + lr;
      bv[ni] = *(const f16x8*)(Bs[db] + row * 32 + ((lg ^ ((row >> 1) & 3)) << 3));
    }
    #pragma unroll
    for(int mi = 0; mi < 4; mi++){
      #pragma unroll
      for(int ni = 0; ni < 4; ni++)
        acc[mi][ni] = mfma16(av[mi], bv[ni], acc[mi][ni]);
    }
    barrier_f();
    db ^= 1;
  }
  #pragma unroll
  for(int mi = 0; mi < 4; mi++){
    #pragma unroll
    for(int ni = 0; ni < 4; ni++){
      #pragma unroll
      for(int j = 0; j < 4; j++){
        int o = o0 + wm + mi * 16 + lg * 4 + j;
        int s = s0 + wn + ni * 16 + lr;
        Ob[(size_t)o * 4096 + s] = (f16)(acc[mi][ni][j] + bp[o]);
      }
    }
  }
}

// ============ 4b. fused 3-output style conv: k (batched W), v, v2 ============
__global__ __launch_bounds__(256) void k_conv3out(
    const f16* __restrict__ Xt,
    const f16* __restrict__ Wk, const f16* __restrict__ Wv, const f16* __restrict__ Wv2,
    const float* __restrict__ biasp,
    f16* __restrict__ Ok, f16* __restrict__ Ov, f16* __restrict__ Ov2)
{
  const int b = blockIdx.z;
  const int seg = blockIdx.y >> 2;
  const int o0 = (blockIdx.y & 3) * 128;
  const int s0 = blockIdx.x * 128;
  const f16* Xb = Xt + (size_t)b * 4096 * 512;
  const f16* Wb = seg == 0 ? Wk + (size_t)b * 262144 : (seg == 1 ? Wv : Wv2);
  const float* bp = biasp + (seg == 0 ? 1 * 2048 + b * 512 : (seg == 1 ? 2 * 2048 : 3 * 2048));
  f16* Ob = (seg == 0 ? Ok : (seg == 1 ? Ov : Ov2)) + (size_t)b * 512 * 4096;
  __shared__ f16 As[2][4096];
  __shared__ f16 Bs[2][4096];
  const int t = threadIdx.x;
  const int lane = t & 63, wid = t >> 6;
  const int wm = (wid >> 1) * 64, wn = (wid & 1) * 64;
  const int lr = lane & 15, lg = lane >> 4;
  const int sr = lane >> 2, sc = lane & 3;
  auto STAGE = [&](int d, int kk){
    #pragma unroll
    for(int i = 0; i < 2; i++){
      int r0 = wid * 32 + i * 16;
      int rr = r0 + sr;
      int cs = (sc ^ ((rr >> 1) & 3)) << 3;
      glds16(Wb + (size_t)(o0 + rr) * 512 + kk + cs, As[d] + r0 * 32);
      glds16(Xb + (size_t)(s0 + rr) * 512 + kk + cs, Bs[d] + r0 * 32);
    }
  };
  f32x4 acc[4][4] = {};
  STAGE(0, 0);
  int db = 0;
  for(int tt = 0; tt < 16; tt++){
    if(tt < 15){
      STAGE(db ^ 1, (tt + 1) * 32);
      asm volatile("s_waitcnt vmcnt(4)" ::: "memory");
    } else {
      asm volatile("s_waitcnt vmcnt(0)" ::: "memory");
    }
    barrier_f();
    f16x8 av[4], bv[4];
    #pragma unroll
    for(int mi = 0; mi < 4; mi++){
      int row = wm + mi * 16 + lr;
      av[mi] = *(const f16x8*)(As[db] + row * 32 + ((lg ^ ((row >> 1) & 3)) << 3));
    }
    #pragma unroll
    for(int ni = 0; ni < 4; ni++){
      int row = wn + ni * 16 + lr;
      bv[ni] = *(const f16x8*)(Bs[db] + row * 32 + ((lg ^ ((row >> 1) & 3)) << 3));
    }
    #pragma unroll
    for(int mi = 0; mi < 4; mi++){
      #pragma unroll
      for(int ni = 0; ni < 4; ni++)
        acc[mi][ni] = mfma16(av[mi], bv[ni], acc[mi][ni]);
    }
    barrier_f();
    db ^= 1;
  }
  #pragma unroll
  for(int mi = 0; mi < 4; mi++){
    #pragma unroll
    for(int ni = 0; ni < 4; ni++){
      #pragma unroll
      for(int j = 0; j < 4; j++){
        int o = o0 + wm + mi * 16 + lg * 4 + j;
        int s = s0 + wn + ni * 16 + lr;
        Ob[(size_t)o * 4096 + s] = (f16)(acc[mi][ni][j] + bp[o]);
      }
    }
  }
}

// ============ 5. PA1 (f16 path) split-K MFMA ============
__global__ __launch_bounds__(256) void k_pa1(
    const f16* __restrict__ Qh, const f16* __restrict__ Kh, float* __restrict__ pa1p)
{
  const int slice = blockIdx.x & 7;
  const int bh = blockIdx.x >> 3;
  const size_t base = (size_t)bh * 64 * 4096;
  __shared__ f16 Ah[2][64][72], Bh[2][64][72];
  const int t = threadIdx.x;
  const int lane = t & 63, wid = t >> 6;
  const int wm = (wid >> 1) * 32, wn = (wid & 1) * 32;
  const int lr = lane & 15, lg = lane >> 4;
  f32x4 acc[2][2] = {};
  for(int chunk = 0; chunk < 4; chunk++){
    const int c0 = slice * 8 + chunk * 2;
    __syncthreads();
    #pragma unroll
    for(int cc = 0; cc < 2; cc++){
      size_t cbase = base + (size_t)(c0 + cc) * 4096;
      #pragma unroll
      for(int u = 0; u < 2; u++){
        int e = u * 256 + t;
        int x = e >> 3, yh = e & 7;
        size_t src = cbase + (size_t)((x >> 3) * 512 + (x & 7) * 8 + yh * 64);
        int dst = yh * 8;
        *(f16x8*)(&Ah[cc][x][dst]) = *(const f16x8*)(Qh + src);
        *(f16x8*)(&Bh[cc][x][dst]) = *(const f16x8*)(Kh + src);
      }
    }
    __syncthreads();
    #pragma unroll
    for(int cc = 0; cc < 2; cc++){
      #pragma unroll
      for(int kc = 0; kc < 2; kc++){
        f16x8 ah[2], bh[2];
        #pragma unroll
        for(int mi = 0; mi < 2; mi++)
          ah[mi] = *(const f16x8*)(&Ah[cc][wm + mi * 16 + lr][kc * 32 + lg * 8]);
        #pragma unroll
        for(int ni = 0; ni < 2; ni++)
          bh[ni] = *(const f16x8*)(&Bh[cc][wn + ni * 16 + lr][kc * 32 + lg * 8]);
        #pragma unroll
        for(int mi = 0; mi < 2; mi++){
          #pragma unroll
          for(int ni = 0; ni < 2; ni++)
            acc[mi][ni] = mfma16(ah[mi], bh[ni], acc[mi][ni]);
        }
      }
    }
  }
  float* outp = pa1p + ((size_t)bh * 8 + slice) * 4096;
  #pragma unroll
  for(int mi = 0; mi < 2; mi++){
    #pragma unroll
    for(int ni = 0; ni < 2; ni++){
      #pragma unroll
      for(int j = 0; j < 4; j++){
        int x = wm + mi * 16 + lg * 4 + j;
        int z = wn + ni * 16 + lr;
        outp[x * 64 + z] = acc[mi][ni][j];
      }
    }
  }
}

// ============ 5b. reduce partials + argmax + near-tie flag ============
__global__ __launch_bounds__(64) void k_pa1r(
    float* __restrict__ pa1p, int* __restrict__ idx, int* __restrict__ flags)
{
  const int bh = blockIdx.x;
  const int x = threadIdx.x;
  float* p = pa1p + (size_t)bh * 8 * 4096 + x * 64;
  float m1 = -3e38f, m2 = -3e38f; int i1 = 0;
  for(int z = 0; z < 64; z += 4){
    float4 v = *(const float4*)(p + z);
    #pragma unroll
    for(int sl = 1; sl < 8; sl++){
      float4 w = *(const float4*)(p + sl * 4096 + z);
      v.x += w.x; v.y += w.y; v.z += w.z; v.w += w.w;
    }
    *(float4*)(p + z) = v;
    float vv[4] = {v.x, v.y, v.z, v.w};
    #pragma unroll
    for(int k = 0; k < 4; k++){
      if(vv[k] > m1){ m2 = m1; m1 = vv[k]; i1 = z + k; }
      else if(vv[k] > m2){ m2 = vv[k]; }
    }
  }
  idx[bh * 64 + x] = i1;
  flags[bh * 64 + x] = (m2 >= m1 - 0.5f) ? 1 : 0;
}

// ============ 5c. exact refinement for near-tie argmax rows (pipelined gemm) ============
__global__ __launch_bounds__(256) void k_refine(
    const f16* __restrict__ Xqh, const f16* __restrict__ Xql,
    const f16* __restrict__ Xkh, const f16* __restrict__ Xkl,
    const f16* __restrict__ Wqh, const f16* __restrict__ Wql,
    const f16* __restrict__ Wkh, const f16* __restrict__ Wkl,
    const float* __restrict__ biasp, const float* __restrict__ pa1p,
    const int* __restrict__ flags, int* __restrict__ idx)
{
  const int bid = blockIdx.x;
  if(flags[bid] == 0) return;
  const int bh = bid >> 6, x = bid & 63;
  const int b = bh >> 3, hd = bh & 7;
  __shared__ __align__(16) f16 Ah[64][72], Al[64][72], Bh[64][72], Bl[64][72];
  __shared__ float q2s[64][65];
  __shared__ float red[4];
  __shared__ float vals[64];
  __shared__ int cand[64];
  const int t = threadIdx.x;
  const int lane = t & 63, wid = t >> 6;
  const int wm = (wid >> 1) * 32, wn = (wid & 1) * 32;
  const int lr = lane & 15, lg = lane >> 4;
  const int srw = t >> 2, soc = (t & 3) * 2;

  auto gemm = [&](const f16* Wh_, const f16* Wl_, const f16* Xh_, const f16* Xl_,
                  int blk, f32x4 (&acc)[2][2]){
    const size_t wrow = ((size_t)(b * 512 + hd * 64 + srw)) * 512 + soc * 8;
    const int s = (blk >> 3) * 512 + (blk & 7) * 8 + (srw >> 3) * 64 + (srw & 7);
    const size_t xrow = ((size_t)b * 4096 + s) * 512 + soc * 8;
    f16x8 r0, r1, r2, r3, r4, r5, r6, r7;
    #define RLOAD(ch, a0,a1,a2,a3,a4,a5,a6,a7) do{            \
      a0 = *(const f16x8*)(Wh_ + wrow + (ch) * 64);           \
      a1 = *(const f16x8*)(Wh_ + wrow + (ch) * 64 + 8);       \
      a2 = *(const f16x8*)(Wl_ + wrow + (ch) * 64);           \
      a3 = *(const f16x8*)(Wl_ + wrow + (ch) * 64 + 8);       \
      a4 = *(const f16x8*)(Xh_ + xrow + (ch) * 64);           \
      a5 = *(const f16x8*)(Xh_ + xrow + (ch) * 64 + 8);       \
      a6 = *(const f16x8*)(Xl_ + xrow + (ch) * 64);           \
      a7 = *(const f16x8*)(Xl_ + xrow + (ch) * 64 + 8);       \
    }while(0)
    RLOAD(0, r0,r1,r2,r3,r4,r5,r6,r7);
    #pragma unroll
    for(int ch = 0; ch < 8; ch++){
      __syncthreads();
      *(f16x8*)(&Ah[srw][soc * 8])     = r0;
      *(f16x8*)(&Ah[srw][soc * 8 + 8]) = r1;
      *(f16x8*)(&Al[srw][soc * 8])     = r2;
      *(f16x8*)(&Al[srw][soc * 8 + 8]) = r3;
      *(f16x8*)(&Bh[srw][soc * 8])     = r4;
      *(f16x8*)(&Bh[srw][soc * 8 + 8]) = r5;
      *(f16x8*)(&Bl[srw][soc * 8])     = r6;
      *(f16x8*)(&Bl[srw][soc * 8 + 8]) = r7;
      f16x8 n0, n1, n2, n3, n4, n5, n6, n7;
      if(ch < 7) RLOAD(ch + 1, n0,n1,n2,n3,n4,n5,n6,n7);
      __syncthreads();
      #pragma unroll
      for(int kc = 0; kc < 2; kc++){
        f16x8 ah[2], al[2], bh2[2], bl2[2];
        #pragma unroll
        for(int mi = 0; mi < 2; mi++){
          int row = wm + mi * 16 + lr;
          ah[mi] = *(const f16x8*)(&Ah[row][kc * 32 + lg * 8]);
          al[mi] = *(const f16x8*)(&Al[row][kc * 32 + lg * 8]);
        }
        #pragma unroll
        for(int ni = 0; ni < 2; ni++){
          int row = wn + ni * 16 + lr;
          bh2[ni] = *(const f16x8*)(&Bh[row][kc * 32 + lg * 8]);
          bl2[ni] = *(const f16x8*)(&Bl[row][kc * 32 + lg * 8]);
        }
        #pragma unroll
        for(int mi = 0; mi < 2; mi++){
          #pragma unroll
          for(int ni = 0; ni < 2; ni++){
            f32x4 a = acc[mi][ni];
            a = mfma16(ah[mi], bh2[ni], a);
            a = mfma16(ah[mi], bl2[ni], a);
            a = mfma16(al[mi], bh2[ni], a);
            acc[mi][ni] = a;
          }
        }
      }
      r0 = n0; r1 = n1; r2 = n2; r3 = n3;
      r4 = n4; r5 = n5; r6 = n6; r7 = n7;
    }
    #undef RLOAD
  };

  if(t < 64) vals[t] = pa1p[(size_t)bh * 8 * 4096 + x * 64 + t];
  __syncthreads();
  if(t == 0){
    float m1 = vals[0];
    for(int z = 1; z < 64; z++) m1 = fmaxf(m1, vals[z]);
    red[0] = m1;
  }
  __syncthreads();
  const float m1 = red[0];
  if(t < 64) cand[t] = (vals[t] >= m1 - 0.5f) ? 1 : 0;
  __syncthreads();

  {
    f32x4 qa[2][2] = {};
    gemm(Wqh, Wql, Xqh, Xql, x, qa);
    #pragma unroll
    for(int mi = 0; mi < 2; mi++){
      #pragma unroll
      for(int ni = 0; ni < 2; ni++){
        #pragma unroll
        for(int j = 0; j < 4; j++){
          int c = wm + mi * 16 + lg * 4 + j;
          int y = wn + ni * 16 + lr;
          q2s[c][y] = qa[mi][ni][j] + biasp[4 * 2048 + b * 512 + hd * 64 + c];
        }
      }
    }
  }
  __syncthreads();

  float bestv = -3e38f; int besti = 0;
  for(int z = 0; z < 64; z++){
    if(!cand[z]) continue;
    f32x4 ka[2][2] = {};
    gemm(Wkh, Wkl, Xkh, Xkl, z, ka);
    float part = 0.f;
    #pragma unroll
    for(int mi = 0; mi < 2; mi++){
      #pragma unroll
      for(int ni = 0; ni < 2; ni++){
        #pragma unroll
        for(int j = 0; j < 4; j++){
          int c = wm + mi * 16 + lg * 4 + j;
          int y = wn + ni * 16 + lr;
          part += (ka[mi][ni][j] + biasp[5 * 2048 + b * 512 + hd * 64 + c]) * q2s[c][y];
        }
      }
    }
    #pragma unroll
    for(int off = 32; off > 0; off >>= 1) part += __shfl_xor(part, off);
    __syncthreads();
    if(lane == 0) red[wid] = part;
    __syncthreads();
    float pv = red[0] + red[1] + red[2] + red[3];
    if(pv > bestv){ bestv = pv; besti = z; }
  }
  if(t == 0) idx[bid] = besti;
}

// ============ 6. DA aggregation — XCD-grouped ============
__global__ __launch_bounds__(256) void k_da1(
    const f16* __restrict__ K, const f16* __restrict__ V,
    const float* __restrict__ alpha_p, const float* __restrict__ beta_p,
    float* __restrict__ kagg, float* __restrict__ vagg)
{
  const int hw = blockIdx.x;
  const int xcd = hw & 7, i = hw >> 3;
  const int g = xcd * 32 + (i >> 3);
  const int bh = g >> 3;
  const int x  = (g & 7) * 8 + (i & 7);
  const f16* Kb = K + (size_t)bh * 64 * 4096;
  const f16* Vb = V + (size_t)bh * 64 * 4096;
  __shared__ float kl[64][65];
  __shared__ float vl[64][65];
  __shared__ float kc[64], vc[64], simv[64];
  const int t = threadIdx.x;
  const int c = t >> 2, yp = t & 3;
  const int xb = (x >> 3) * 512 + (x & 7) * 8;
  #pragma unroll
  for(int u = 0; u < 2; u++){
    int yh = yp * 2 + u;
    f16x8 k8 = *(const f16x8*)(Kb + (size_t)c * 4096 + xb + yh * 64);
    f16x8 v8 = *(const f16x8*)(Vb + (size_t)c * 4096 + xb + yh * 64);
    #pragma unroll
    for(int j = 0; j < 8; j++){
      kl[c][yh * 8 + j] = (float)k8[j];
      vl[c][yh * 8 + j] = (float)v8[j];
    }
  }
  __syncthreads();
  float sk = 0.f, sv = 0.f;
  for(int yy = yp * 16; yy < yp * 16 + 16; yy++){ sk += kl[c][yy]; sv += vl[c][yy]; }
  sk += __shfl_xor(sk, 1); sk += __shfl_xor(sk, 2);
  sv += __shfl_xor(sv, 1); sv += __shfl_xor(sv, 2);
  if(yp == 0){ kc[c] = sk * (1.f / 64.f); vc[c] = sv * (1.f / 64.f); }
  __syncthreads();
  const int y = t >> 2, cp = t & 3;
  float d = 0.f;
  for(int cc = cp * 16; cc < cp * 16 + 16; cc++) d += kc[cc] * kl[cc][y];
  d += __shfl_xor(d, 1); d += __shfl_xor(d, 2);
  if(cp == 0) simv[y] = 1.f / (1.f + expf(-(beta_p[0] + alpha_p[0] * d)));
  __syncthreads();
  float ak = 0.f, av = 0.f;
  for(int yy = yp * 16; yy < yp * 16 + 16; yy++){
    float sm = simv[yy];
    ak += sm * kl[c][yy]; av += sm * vl[c][yy];
  }
  ak += __shfl_xor(ak, 1); ak += __shfl_xor(ak, 2);
  av += __shfl_xor(av, 1); av += __shfl_xor(av, 2);
  if(yp == 0){
    size_t o = ((size_t)bh * 64 + x) * 64 + c;
    kagg[o] = (ak + kc[c]) * (1.f / 65.f);
    vagg[o] = (av + vc[c]) * (1.f / 65.f);
  }
}

// ============ 7. DA attention MFMA; output TRANSPOSED [s][c] ============
__global__ __launch_bounds__(256) void k_da2(
    const f16* __restrict__ Q, const float* __restrict__ kagg,
    const float* __restrict__ vagg, f16* __restrict__ OutT)
{
  const int bh = blockIdx.x >> 4;
  const int s0 = (blockIdx.x & 15) << 8;
  const int b_ = bh >> 3, hd = bh & 7;
  const f16* Qb = Q + (size_t)bh * 64 * 4096;
  f16* Ot = OutT + (size_t)b_ * 4096 * 512 + hd * 64;

  __shared__ __align__(16) f16 Qt[256][72];
  __shared__ __align__(16) f16 Kt[64][72];
  __shared__ __align__(16) f16 Vt[64][72];
  const int t = threadIdx.x;
  const int lane = t & 63, w = t >> 6;
  const int lr = lane & 15, lg = lane >> 4;

  {
    const int so = t & 31;
    #pragma unroll
    for(int pass = 0; pass < 8; pass++){
      int c = (t >> 5) + pass * 8;
      f16x8 q8 = *(const f16x8*)(Qb + (size_t)c * 4096 + s0 + so * 8);
      #pragma unroll
      for(int j = 0; j < 8; j++){
        int s = so * 8 + j;
        int col = (((c >> 3) ^ (s & 7)) << 3) | (c & 7);
        Qt[s][col] = q8[j];
      }
    }
  }
  {
    const int z = t >> 2, c0 = (t & 3) * 16;
    #pragma unroll
    for(int u = 0; u < 4; u++){
      float4 v = *(const float4*)(kagg + (size_t)bh * 4096 + z * 64 + c0 + u * 4);
      float vv[4] = {v.x, v.y, v.z, v.w};
      #pragma unroll
      for(int j = 0; j < 4; j++){
        int c = c0 + u * 4 + j;
        int col = (((c >> 3) ^ (z & 7)) << 3) | (c & 7);
        Kt[z][col] = (f16)vv[j];
      }
    }
    #pragma unroll
    for(int u = 0; u < 4; u++){
      float4 v = *(const float4*)(vagg + (size_t)bh * 4096 + z * 64 + c0 + u * 4);
      float vv[4] = {v.x, v.y, v.z, v.w};
      #pragma unroll
      for(int j = 0; j < 4; j++){
        int c = c0 + u * 4 + j;
        int col = (((z >> 3) ^ (c & 7)) << 3) | (z & 7);
        Vt[c][col] = (f16)vv[j];
      }
    }
  }
  __syncthreads();

  f32x4 acc[4][4] = {};
  #pragma unroll
  for(int kc = 0; kc < 2; kc++){
    f16x8 af[4], bf[4];
    #pragma unroll
    for(int mi = 0; mi < 4; mi++){
      int row = w * 64 + mi * 16 + lr;
      af[mi] = *(const f16x8*)(&Qt[row][(((kc * 4 + lg) ^ (row & 7)) << 3)]);
    }
    #pragma unroll
    for(int ni = 0; ni < 4; ni++){
      int row = ni * 16 + lr;
      bf[ni] = *(const f16x8*)(&Kt[row][(((kc * 4 + lg) ^ (row & 7)) << 3)]);
    }
    #pragma unroll
    for(int mi = 0; mi < 4; mi++){
      #pragma unroll
      for(int ni = 0; ni < 4; ni++)
        acc[mi][ni] = mfma16(af[mi], bf[ni], acc[mi][ni]);
    }
  }

  #pragma unroll
  for(int mi = 0; mi < 4; mi++){
    #pragma unroll
    for(int j = 0; j < 4; j++){
      float v0 = acc[mi][0][j], v1 = acc[mi][1][j], v2 = acc[mi][2][j], v3 = acc[mi][3][j];
      float m = fmaxf(fmaxf(v0, v1), fmaxf(v2, v3));
      m = fmaxf(m, __shfl_xor(m, 1)); m = fmaxf(m, __shfl_xor(m, 2));
      m = fmaxf(m, __shfl_xor(m, 4)); m = fmaxf(m, __shfl_xor(m, 8));
      float e0 = expf(v0 - m), e1 = expf(v1 - m), e2 = expf(v2 - m), e3 = expf(v3 - m);
      float sm = e0 + e1 + e2 + e3;
      sm += __shfl_xor(sm, 1); sm += __shfl_xor(sm, 2);
      sm += __shfl_xor(sm, 4); sm += __shfl_xor(sm, 8);
      float inv = 1.f / sm;
      float ev[4] = {e0, e1, e2, e3};
      int row = w * 64 + mi * 16 + lg * 4 + j;
      #pragma unroll
      for(int ni = 0; ni < 4; ni++){
        int z = lr + 16 * ni;
        int col = (((z >> 3) ^ (row & 7)) << 3) | (z & 7);
        Qt[row][col] = (f16)(ev[ni] * inv);
      }
    }
  }

  f32x4 acc2[4][4] = {};
  #pragma unroll
  for(int kc = 0; kc < 2; kc++){
    f16x8 af[4], bf[4];
    #pragma unroll
    for(int mi = 0; mi < 4; mi++){
      int row = w * 64 + mi * 16 + lr;
      af[mi] = *(const f16x8*)(&Qt[row][(((kc * 4 + lg) ^ (row & 7)) << 3)]);
    }
    #pragma unroll
    for(int ni = 0; ni < 4; ni++){
      int row = ni * 16 + lr;
      bf[ni] = *(const f16x8*)(&Vt[row][(((kc * 4 + lg) ^ (row & 7)) << 3)]);
    }
    #pragma unroll
    for(int mi = 0; mi < 4; mi++){
      #pragma unroll
      for(int ni = 0; ni < 4; ni++)
        acc2[mi][ni] = mfma16(af[mi], bf[ni], acc2[mi][ni]);
    }
  }

  #pragma unroll
  for(int mi = 0; mi < 4; mi++){
    #pragma unroll
    for(int j = 0; j < 4; j++){
      size_t srow = (size_t)(s0 + w * 64 + mi * 16 + lg * 4 + j) * 512;
      #pragma unroll
      for(int ni = 0; ni < 4; ni++)
        Ot[srow + ni * 16 + lr] = (f16)acc2[mi][ni][j];
    }
  }
}

// ============ 9. PA intra-block attention; output TRANSPOSED [s][c] ============
__global__ __launch_bounds__(256) void k_pa2(
    const f16* __restrict__ Qh, const f16* __restrict__ Kh,
    const f16* __restrict__ V2, const int* __restrict__ idx, f16* __restrict__ OutT)
{
  const int hw = blockIdx.x;
  const int bh = (hw & 7) * 4 + ((hw >> 3) >> 6);
  const int x  = (hw >> 3) & 63;
  const int b_ = bh >> 3, hd = bh & 7;
  const size_t base = (size_t)bh * 64 * 4096;
  f16* Ot = OutT + (size_t)b_ * 4096 * 512 + hd * 64;

  __shared__ __align__(16) char Ubuf[18432];
  __shared__ f16 Vn[64][72];
  __shared__ f16 Ps[64][72];
  f16   (*Qt)[72] = (f16(*)[72])Ubuf;
  f16   (*Kt)[72] = (f16(*)[72])(Ubuf + 9216);
  float (*Lf)[66] = (float(*)[66])Ubuf;
  float (*Os)[67] = (float(*)[67])Ubuf;

  const int t = threadIdx.x;
  const int lane = t & 63, wid = t >> 6;
  const int wm = (wid >> 1) * 32, wn = (wid & 1) * 32;
  const int lr = lane & 15, lg = lane >> 4;

  const int xk = idx[bh * 64 + x];
  const int xb = (x >> 3) * 512 + (x & 7) * 8;
  const int kb = (xk >> 3) * 512 + (xk & 7) * 8;

  {
    const int c = t >> 2, q4 = t & 3;
    #pragma unroll
    for(int u = 0; u < 2; u++){
      int yh = q4 * 2 + u;
      f16x8 q8 = *(const f16x8*)(Qh + base + (size_t)c * 4096 + xb + yh * 64);
      f16x8 k8 = *(const f16x8*)(Kh + base + (size_t)c * 4096 + kb + yh * 64);
      f16x8 v8 = *(const f16x8*)(V2 + base + (size_t)c * 4096 + kb + yh * 64);
      int col = ((((c >> 3) ^ yh) & 7) << 3) + (c & 7);
      #pragma unroll
      for(int j = 0; j < 8; j++){
        Qt[yh * 8 + j][col] = q8[j];
        Kt[yh * 8 + j][col] = k8[j];
      }
      *(f16x8*)(&Vn[c][yh * 8]) = v8;
    }
  }
  __syncthreads();

  f32x4 acc[2][2] = {};
  #pragma unroll
  for(int kc = 0; kc < 2; kc++){
    f16x8 af[2], bf[2];
    #pragma unroll
    for(int mi = 0; mi < 2; mi++){
      int row = wm + mi * 16 + lr;
      af[mi] = *(const f16x8*)(&Qt[row][((((kc * 4 + lg) ^ (row >> 3)) & 7) << 3)]);
    }
    #pragma unroll
    for(int ni = 0; ni < 2; ni++){
      int row = wn + ni * 16 + lr;
      bf[ni] = *(const f16x8*)(&Kt[row][((((kc * 4 + lg) ^ (row >> 3)) & 7) << 3)]);
    }
    #pragma unroll
    for(int mi = 0; mi < 2; mi++){
      #pragma unroll
      for(int ni = 0; ni < 2; ni++)
        acc[mi][ni] = mfma16(af[mi], bf[ni], acc[mi][ni]);
    }
  }
  __syncthreads();
  #pragma unroll
  for(int mi = 0; mi < 2; mi++){
    #pragma unroll
    for(int ni = 0; ni < 2; ni++){
      #pragma unroll
      for(int j = 0; j < 4; j++)
        Lf[wm + mi * 16 + lg * 4 + j][wn + ni * 16 + lr] = acc[mi][ni][j];
    }
  }
  __syncthreads();

  {
    const int y = t >> 2, zp = t & 3;
    float l[16];
    #pragma unroll
    for(int i = 0; i < 16; i++) l[i] = Lf[y][zp * 16 + i];
    float m = l[0];
    #pragma unroll
    for(int i = 1; i < 16; i++) m = fmaxf(m, l[i]);
    m = fmaxf(m, __shfl_xor(m, 1)); m = fmaxf(m, __shfl_xor(m, 2));
    float sum = 0.f;
    #pragma unroll
    for(int i = 0; i < 16; i++){ l[i] = expf(l[i] - m); sum += l[i]; }
    sum += __shfl_xor(sum, 1); sum += __shfl_xor(sum, 2);
    float inv = 1.f / sum;
    f16x8 p0, p1;
    #pragma unroll
    for(int i = 0; i < 8; i++){ p0[i] = (f16)(l[i] * inv); p1[i] = (f16)(l[8 + i] * inv); }
    *(f16x8*)(&Ps[y][zp * 16]) = p0;
    *(f16x8*)(&Ps[y][zp * 16 + 8]) = p1;
  }
  __syncthreads();

  f32x4 acc2[2][2] = {};
  #pragma unroll
  for(int kc = 0; kc < 2; kc++){
    f16x8 af[2], bf[2];
    #pragma unroll
    for(int mi = 0; mi < 2; mi++)
      af[mi] = *(const f16x8*)(&Ps[wm + mi * 16 + lr][kc * 32 + lg * 8]);
    #pragma unroll
    for(int ni = 0; ni < 2; ni++)
      bf[ni] = *(const f16x8*)(&Vn[wn + ni * 16 + lr][kc * 32 + lg * 8]);
    #pragma unroll
    for(int mi = 0; mi < 2; mi++){
      #pragma unroll
      for(int ni = 0; ni < 2; ni++)
        acc2[mi][ni] = mfma16(af[mi], bf[ni], acc2[mi][ni]);
    }
  }
  #pragma unroll
  for(int mi = 0; mi < 2; mi++){
    #pragma unroll
    for(int ni = 0; ni < 2; ni++){
      #pragma unroll
      for(int j = 0; j < 4; j++)
        Os[wn + ni * 16 + lr][wm + mi * 16 + lg * 4 + j] = acc2[mi][ni][j];
    }
  }
  __syncthreads();

  {
    const int y = t >> 2, cq = (t & 3) * 16;
    size_t srow = (size_t)(xb + (y >> 3) * 64 + (y & 7)) * 512;
    f16x8 w0, w1;
    #pragma unroll
    for(int i = 0; i < 8; i++){ w0[i] = (f16)Os[cq + i][y]; w1[i] = (f16)Os[cq + 8 + i][y]; }
    *(f16x8*)(Ot + srow + cq) = w0;
    *(f16x8*)(Ot + srow + cq + 8) = w1;
  }
}

// ============ 10. Final: 128x128 tile, 2 passes ============
__global__ __launch_bounds__(256) void k_finalT(
    const f16* __restrict__ X1t, const f16* __restrict__ X2t,
    const f16* __restrict__ W1p, const f16* __restrict__ W2p,
    const float* __restrict__ B1, const float* __restrict__ B2,
    const float* __restrict__ content, float* __restrict__ out)
{
  const int b = blockIdx.z;
  const int o0 = blockIdx.y * 128;
  const int s0 = blockIdx.x * 128;
  __shared__ f16 As[2][4096];
  __shared__ f16 Bs[2][4096];
  const int t = threadIdx.x;
  const int lane = t & 63, wid = t >> 6;
  const int wm = (wid >> 1) * 64, wn = (wid & 1) * 64;
  const int lr = lane & 15, lg = lane >> 4;
  const int sr = lane >> 2, sc = lane & 3;
  const f16* Xp[2] = {X1t + (size_t)b * 4096 * 512, X2t + (size_t)b * 4096 * 512};
  const f16* Wq[2] = {W1p, W2p};
  auto STAGE = [&](int d, int tt){
    const f16* Xb = Xp[tt >> 4];
    const f16* Wb = Wq[tt >> 4];
    int kk = (tt & 15) * 32;
    #pragma unroll
    for(int i = 0; i < 2; i++){
      int r0 = wid * 32 + i * 16;
      int rr = r0 + sr;
      int cs = (sc ^ ((rr >> 1) & 3)) << 3;
      glds16(Wb + (size_t)(o0 + rr) * 512 + kk + cs, As[d] + r0 * 32);
      glds16(Xb + (size_t)(s0 + rr) * 512 + kk + cs, Bs[d] + r0 * 32);
    }
  };
  f32x4 acc[4][4] = {};
  STAGE(0, 0);
  int db = 0;
  for(int tt = 0; tt < 32; tt++){
    if(tt < 31){
      STAGE(db ^ 1, tt + 1);
      asm volatile("s_waitcnt vmcnt(4)" ::: "memory");
    } else {
      asm volatile("s_waitcnt vmcnt(0)" ::: "memory");
    }
    barrier_f();
    f16x8 av[4], bv[4];
    #pragma unroll
    for(int mi = 0; mi < 4; mi++){
      int row = wm + mi * 16 + lr;
      av[mi] = *(const f16x8*)(As[db] + row * 32 + ((lg ^ ((row >> 1) & 3)) << 3));
    }
    #pragma unroll
    for(int ni = 0; ni < 4; ni++){
      int row = wn + ni * 16 + lr;
      bv[ni] = *(const f16x8*)(Bs[db] + row * 32 + ((lg ^ ((row >> 1) & 3)) << 3));
    }
    #pragma unroll
    for(int mi = 0; mi < 4; mi++){
      #pragma unroll
      for(int ni = 0; ni < 4; ni++)
        acc[mi][ni] = mfma16(av[mi], bv[ni], acc[mi][ni]);
    }
    barrier_f();
    db ^= 1;
  }
  #pragma unroll
  for(int mi = 0; mi < 4; mi++){
    #pragma unroll
    for(int ni = 0; ni < 4; ni++){
      #pragma unroll
      for(int j = 0; j < 4; j++){
        int o = o0 + wm + mi * 16 + lg * 4 + j;
        int s = s0 + wn + ni * 16 + lr;
        size_t gi = ((size_t)b * 512 + o) * 4096 + s;
        out[gi] = acc[mi][ni][j] + B1[o] + B2[o] + content[gi];
      }
    }
  }
}

extern "C" void kernel_launch(void* const* d_in, const int* in_sizes, int n_in,
                              void* d_out, int out_size, void* d_ws, size_t ws_size,
                              hipStream_t stream) {
  (void)in_sizes; (void)n_in; (void)out_size; (void)ws_size;
  const float* content = (const float*)d_in[0];
  const float* style   = (const float*)d_in[1];
  const float* q_w  = (const float*)d_in[2];  const float* q_b  = (const float*)d_in[3];
  const float* k_w  = (const float*)d_in[4];  const float* k_b  = (const float*)d_in[5];
  const float* v_w  = (const float*)d_in[6];  const float* v_b  = (const float*)d_in[7];
  const float* q2_w = (const float*)d_in[8];  const float* q2_b = (const float*)d_in[9];
  const float* k2_w = (const float*)d_in[10]; const float* k2_b = (const float*)d_in[11];
  const float* v2_w = (const float*)d_in[12]; const float* v2_b = (const float*)d_in[13];
  const float* f1_w = (const float*)d_in[14]; const float* f1_b = (const float*)d_in[15];
  const float* f2_w = (const float*)d_in[16]; const float* f2_b = (const float*)d_in[17];
  const float* sim_alpha = (const float*)d_in[18];
  const float* sim_beta  = (const float*)d_in[19];

  char* ws = (char*)d_ws;
  #define SLOT(i) (ws + (size_t)(i) * 16777216)
  f16* cth = (f16*)SLOT(0);
  f16* ctl = (f16*)SLOT(1);
  f16* sth = (f16*)SLOT(2);
  f16* stl = (f16*)SLOT(3);
  f16* wbase = (f16*)SLOT(4);
  f16* qw   = wbase;
  f16* kw   = wbase + 1 * 1048576;
  f16* q2wh = wbase + 2 * 1048576;
  f16* q2wl = wbase + 3 * 1048576;
  f16* k2wh = wbase + 4 * 1048576;
  f16* k2wl = wbase + 5 * 1048576;
  f16* vw   = wbase + 6 * 1048576;
  f16* v2w  = vw + 262144;
  f16* f1w  = vw + 524288;
  f16* f2w  = vw + 786432;
  f16*   q2h   = (f16*)SLOT(5);
  f16*   k2h   = (f16*)SLOT(6);
  float* pa1p  = (float*)SLOT(7);
  int*   flags = (int*)(ws + 7 * 16777216 + 8388608);
  f16*   qbuf  = (f16*)SLOT(3);      // stl dead after refine
  f16*   kbuf  = (f16*)SLOT(0);      // cth dead after convT(q)
  f16*   vbuf  = (f16*)SLOT(1);      // ctl dead after refine
  f16*   v2buf = (f16*)SLOT(7);      // pa1p/flags dead after refine
  f16*   da_t  = (f16*)SLOT(2);      // sth dead after conv3out
  f16*   pa_t  = (f16*)SLOT(3);      // qbuf dead after da2
  float* stats = (float*)(ws + 134217728);
  float* biasp = (float*)(ws + 134217728 + 32768);
  float* kagg  = (float*)(ws + 134217728 + 32768);
  float* vagg  = (float*)(ws + 134217728 + 557056);
  int*   idxb  = (int*)(ws + 134217728 + 1081344);

  dim3 gconv(32, 4, 4);

  // zero raw-moment accumulators (S/SS), then prep_x accumulates them
  hipMemsetAsync(stats, 0, 32768, stream);

  // c-chunked grid: 1024 blocks (4/CU) instead of 256 (1/CU)
  k_prep_x<<<dim3(32,16,2), 256, 0, stream>>>(content, style, cth, ctl, sth, stl, stats);

  k_prep_w_all<<<320, 256, 0, stream>>>(
      q_w, q_b, k_w, k_b, q2_w, q2_b, k2_w, k2_b,
      v_w, v_b, v2_w, v2_b, f1_w, f2_w, stats,
      qw, kw, q2wh, q2wl, k2wh, k2wl, vw, v2w, f1w, f2w, biasp);

  // q2/k2 projections in plain f16 (argmax near-ties repaired by k_refine)
  k_convT<<<gconv, 256, 0, stream>>>(cth, q2wh, biasp + 4 * 2048, 1, q2h);
  k_convT<<<gconv, 256, 0, stream>>>(sth, k2wh, biasp + 5 * 2048, 1, k2h);
  k_pa1<<<256, 256, 0, stream>>>(q2h, k2h, pa1p);
  k_pa1r<<<32, 64, 0, stream>>>(pa1p, idxb, flags);
  k_refine<<<2048, 256, 0, stream>>>(cth, ctl, sth, stl,
                                     q2wh, q2wl, k2wh, k2wl,
                                     biasp, pa1p, flags, idxb);

  k_convT<<<gconv, 256, 0, stream>>>(cth, qw, biasp + 0 * 2048, 1, qbuf);
  k_conv3out<<<dim3(32,12,4), 256, 0, stream>>>(sth, kw, vw, v2w, biasp,
                                                kbuf, vbuf, v2buf);

  k_da1<<<2048, 256, 0, stream>>>(kbuf, vbuf, sim_alpha, sim_beta, kagg, vagg);
  k_da2<<<512, 256, 0, stream>>>(qbuf, kagg, vagg, da_t);
  k_pa2<<<2048, 256, 0, stream>>>(q2h, k2h, v2buf, idxb, pa_t);

  k_finalT<<<gconv, 256, 0, stream>>>(da_t, pa_t, f1w, f2w, f1_b, f2_b,
                                      content, (float*)d_out);
}